// Round 1
// baseline (678.176 us; speedup 1.0000x reference)
//
#include <hip/hip_runtime.h>
#include <hip/hip_bf16.h>

// ---------------------------------------------------------------------------
// GIN model: 3x (CSR aggregate + 2-layer MLP) + mean-pool + 2-layer head.
// fp32 throughout. CSR rebuilt each call (deterministic-work requirement).
// ---------------------------------------------------------------------------

__global__ void zero_int_kernel(int* __restrict__ p, int n) {
    int i = blockIdx.x * blockDim.x + threadIdx.x;
    if (i < n) p[i] = 0;
}

__global__ void hist_kernel(const int* __restrict__ ei, int* __restrict__ deg, int E_) {
    int e = blockIdx.x * blockDim.x + threadIdx.x;
    if (e < E_) atomicAdd(&deg[ei[E_ + e]], 1);
}

// Block-wise exclusive scan: 256 threads x 4 elems = 1024 per block.
__global__ void scan_blocks_kernel(const int* __restrict__ deg, int* __restrict__ rowptr,
                                   int* __restrict__ part, int n) {
    __shared__ int sd[256];
    const int tid = threadIdx.x;
    const int base = blockIdx.x * 1024 + tid * 4;
    int v[4];
#pragma unroll
    for (int i = 0; i < 4; i++) {
        int idx = base + i;
        v[i] = (idx < n) ? deg[idx] : 0;
    }
    int s = v[0] + v[1] + v[2] + v[3];
    sd[tid] = s;
    __syncthreads();
    for (int off = 1; off < 256; off <<= 1) {
        int x = (tid >= off) ? sd[tid - off] : 0;
        __syncthreads();
        sd[tid] += x;
        __syncthreads();
    }
    int incl = sd[tid];
    int run = incl - s;  // exclusive base for this thread
#pragma unroll
    for (int i = 0; i < 4; i++) {
        int idx = base + i;
        if (idx < n) rowptr[idx] = run;
        run += v[i];
    }
    if (tid == 0) part[blockIdx.x] = sd[255];
}

// Single-block exclusive scan of block partials (nb <= 128).
__global__ void scan_part_kernel(int* __restrict__ part, int nb) {
    __shared__ int sd[128];
    const int tid = threadIdx.x;
    int v = (tid < nb) ? part[tid] : 0;
    sd[tid] = v;
    __syncthreads();
    for (int off = 1; off < 128; off <<= 1) {
        int x = (tid >= off) ? sd[tid - off] : 0;
        __syncthreads();
        sd[tid] += x;
        __syncthreads();
    }
    if (tid < nb) part[tid] = sd[tid] - v;  // exclusive
}

__global__ void add_offsets_kernel(int* __restrict__ rowptr, int* __restrict__ cursor,
                                   const int* __restrict__ part, int n, int E_) {
    int idx = blockIdx.x * blockDim.x + threadIdx.x;
    if (idx < n) {
        int r = rowptr[idx] + part[idx >> 10];
        rowptr[idx] = r;
        cursor[idx] = r;
    }
    if (idx == 0) rowptr[n] = E_;
}

__global__ void fill_kernel(const int* __restrict__ ei, int* __restrict__ cursor,
                            int* __restrict__ col, int E_) {
    int e = blockIdx.x * blockDim.x + threadIdx.x;
    if (e < E_) {
        int d = ei[E_ + e];
        int pos = atomicAdd(&cursor[d], 1);
        col[pos] = ei[e];
    }
}

// ---------------------------------------------------------------------------
// Fused GIN layer: tile of 64 nodes per block, 256 threads.
// Phase A: z = h + sum_nbr h[nbr]  -> LDS (4 threads per node)
// Phase B: t = relu(z @ w1 + b1)   (lane = node, wave = 16-feature quarter,
//          weights via scalar loads)
// Phase C: hout = relu(t @ w2 + b2)
// ---------------------------------------------------------------------------
template <int F>
__global__ __launch_bounds__(256) void gin_layer_kernel(
    const float* __restrict__ hin, float* __restrict__ hout,
    const int* __restrict__ rowptr, const int* __restrict__ col,
    const float* __restrict__ w1, const float* __restrict__ b1,
    const float* __restrict__ w2, const float* __restrict__ b2, int n) {
    __shared__ float zs[64][F + 1];
    __shared__ float ts[64][65];
    const int tid = threadIdx.x;
    const int tile = blockIdx.x;

    // ---- Phase A: aggregation ----
    {
        const int nl = tid >> 2;  // local node 0..63
        const int fq = tid & 3;   // feature quarter
        constexpr int FC = F / 4; // 32 (F=128) or 16 (F=64)
        const int node = tile * 64 + nl;
        if (node < n) {
            float acc[FC];
            const float* hrow = hin + (size_t)node * F + fq * FC;
#pragma unroll
            for (int i = 0; i < FC; i++) acc[i] = hrow[i];
            const int rs = rowptr[node];
            const int re = rowptr[node + 1];
            for (int p = rs; p < re; ++p) {
                const int nb = col[p];
                const float* nrow = hin + (size_t)nb * F + fq * FC;
#pragma unroll
                for (int i = 0; i < FC; i += 4) {
                    float4 v = *reinterpret_cast<const float4*>(nrow + i);
                    acc[i + 0] += v.x;
                    acc[i + 1] += v.y;
                    acc[i + 2] += v.z;
                    acc[i + 3] += v.w;
                }
            }
#pragma unroll
            for (int i = 0; i < FC; i++) zs[nl][fq * FC + i] = acc[i];
        }
    }
    __syncthreads();

    // ---- Phase B: t = relu(z @ w1 + b1) ----
    const int lane = tid & 63;
    const int q = __builtin_amdgcn_readfirstlane(tid >> 6);  // wave id 0..3
    const int j0 = q * 16;
    float a[16];
#pragma unroll
    for (int jj = 0; jj < 16; jj++) a[jj] = b1[j0 + jj];
    for (int k = 0; k < F; k++) {
        const float zk = zs[lane][k];
#pragma unroll
        for (int jj = 0; jj < 16; jj++) a[jj] = fmaf(zk, w1[k * 64 + j0 + jj], a[jj]);
    }
#pragma unroll
    for (int jj = 0; jj < 16; jj++) ts[lane][j0 + jj] = fmaxf(a[jj], 0.f);
    __syncthreads();

    // ---- Phase C: hout = relu(t @ w2 + b2) ----
#pragma unroll
    for (int jj = 0; jj < 16; jj++) a[jj] = b2[j0 + jj];
    for (int k = 0; k < 64; k++) {
        const float tk = ts[lane][k];
#pragma unroll
        for (int jj = 0; jj < 16; jj++) a[jj] = fmaf(tk, w2[k * 64 + j0 + jj], a[jj]);
    }
    const int node = tile * 64 + lane;
    if (node < n) {
        float* orow = hout + (size_t)node * 64 + j0;
#pragma unroll
        for (int jj = 0; jj < 16; jj++) orow[jj] = fmaxf(a[jj], 0.f);
    }
}

// ---------------------------------------------------------------------------
// Mean-pool per graph (batch sorted) + 2-layer head. One block per graph.
// ---------------------------------------------------------------------------
__global__ __launch_bounds__(256) void pool_head_kernel(
    const float* __restrict__ h, const int* __restrict__ batch,
    const float* __restrict__ l1w, const float* __restrict__ l1b,
    const float* __restrict__ l2w, const float* __restrict__ l2b,
    float* __restrict__ out, int n) {
    const int g = blockIdx.x;
    const int tid = threadIdx.x;
    // lower_bound over sorted batch
    auto lb = [&](int key) {
        int lo = 0, hi = n;
        while (lo < hi) {
            int mid = (lo + hi) >> 1;
            if (batch[mid] < key) lo = mid + 1;
            else hi = mid;
        }
        return lo;
    };
    const int lo = lb(g), hi = lb(g + 1);
    const int cnt = hi - lo;

    const int f = tid & 63;
    const int part = tid >> 6;
    float s = 0.f;
    for (int i = lo + part; i < hi; i += 4) s += h[(size_t)i * 64 + f];

    __shared__ float red[256];
    __shared__ float pooled[64];
    __shared__ float r[64];
    red[tid] = s;
    __syncthreads();
    if (tid < 64) {
        float v = red[tid] + red[tid + 64] + red[tid + 128] + red[tid + 192];
        pooled[tid] = v / (float)((cnt > 1) ? cnt : 1);
    }
    __syncthreads();
    if (tid < 64) {
        float a = l1b[tid];
        for (int k = 0; k < 64; k++) a = fmaf(pooled[k], l1w[k * 64 + tid], a);
        r[tid] = fmaxf(a, 0.f);
    }
    __syncthreads();
    if (tid < 2) {
        float a = l2b[tid];
        for (int k = 0; k < 64; k++) a = fmaf(r[k], l2w[k * 2 + tid], a);
        out[g * 2 + tid] = a;
    }
}

// ---------------------------------------------------------------------------

extern "C" void kernel_launch(void* const* d_in, const int* in_sizes, int n_in,
                              void* d_out, int out_size, void* d_ws, size_t ws_size,
                              hipStream_t stream) {
    const float* x    = (const float*)d_in[0];
    const int* ei     = (const int*)d_in[1];
    const int* batch  = (const int*)d_in[2];
    const float* l0w1 = (const float*)d_in[3];
    const float* l0b1 = (const float*)d_in[4];
    const float* l0w2 = (const float*)d_in[5];
    const float* l0b2 = (const float*)d_in[6];
    const float* l1w1 = (const float*)d_in[7];
    const float* l1b1 = (const float*)d_in[8];
    const float* l1w2 = (const float*)d_in[9];
    const float* l1b2 = (const float*)d_in[10];
    const float* l2w1 = (const float*)d_in[11];
    const float* l2b1 = (const float*)d_in[12];
    const float* l2w2 = (const float*)d_in[13];
    const float* l2b2 = (const float*)d_in[14];
    const float* lin1w = (const float*)d_in[15];
    const float* lin1b = (const float*)d_in[16];
    const float* lin2w = (const float*)d_in[17];
    const float* lin2b = (const float*)d_in[18];
    float* out = (float*)d_out;

    const int N  = in_sizes[2];          // batch has N elements
    const int E_ = in_sizes[1] / 2;      // edge_index is (2, E)

    // workspace layout
    char* ws = (char*)d_ws;
    size_t off = 0;
    auto alloc = [&](size_t bytes) {
        void* p = ws + off;
        off += (bytes + 255) & ~(size_t)255;
        return p;
    };
    int* rowptr  = (int*)alloc((size_t)(N + 1) * 4);
    int* degcur  = (int*)alloc((size_t)N * 4);   // deg, then cursor
    int* part    = (int*)alloc(128 * 4);
    int* col     = (int*)alloc((size_t)E_ * 4);
    float* hA    = (float*)alloc((size_t)N * 64 * 4);
    float* hB    = (float*)alloc((size_t)N * 64 * 4);
    (void)ws_size;

    const int NB = (N + 1023) / 1024;  // scan blocks (98 for N=100000)

    // --- CSR build ---
    zero_int_kernel<<<(N + 255) / 256, 256, 0, stream>>>(degcur, N);
    hist_kernel<<<(E_ + 255) / 256, 256, 0, stream>>>(ei, degcur, E_);
    scan_blocks_kernel<<<NB, 256, 0, stream>>>(degcur, rowptr, part, N);
    scan_part_kernel<<<1, 128, 0, stream>>>(part, NB);
    add_offsets_kernel<<<(N + 255) / 256, 256, 0, stream>>>(rowptr, degcur, part, N, E_);
    fill_kernel<<<(E_ + 255) / 256, 256, 0, stream>>>(ei, degcur, col, E_);

    // --- 3 GIN layers ---
    const int ntiles = (N + 63) / 64;
    gin_layer_kernel<128><<<ntiles, 256, 0, stream>>>(x, hA, rowptr, col,
                                                      l0w1, l0b1, l0w2, l0b2, N);
    gin_layer_kernel<64><<<ntiles, 256, 0, stream>>>(hA, hB, rowptr, col,
                                                     l1w1, l1b1, l1w2, l1b2, N);
    gin_layer_kernel<64><<<ntiles, 256, 0, stream>>>(hB, hA, rowptr, col,
                                                     l2w1, l2b1, l2w2, l2b2, N);

    // --- pool + head ---
    pool_head_kernel<<<64, 256, 0, stream>>>(hA, batch, lin1w, lin1b, lin2w, lin2b, out, N);
}

// Round 2
// 602.377 us; speedup vs baseline: 1.1258x; 1.1258x over previous
//
#include <hip/hip_runtime.h>
#include <hip/hip_bf16.h>

// ---------------------------------------------------------------------------
// GIN model, proj-first formulation:
//   per layer: y = h @ w1  (linearity: aggregate AFTER projecting, 64-wide)
//              t = relu(y_self + sum_nbr y + b1)
//              h' = relu(t @ w2 + b2)           (fused with next layer's proj)
// CSR rebuilt each call. fp32 throughout.
// ---------------------------------------------------------------------------

__global__ void zero_int_kernel(int* __restrict__ p, int n) {
    int i = blockIdx.x * blockDim.x + threadIdx.x;
    if (i < n) p[i] = 0;
}

__global__ void hist_kernel(const int* __restrict__ ei, int* __restrict__ deg, int E_) {
    int e = blockIdx.x * blockDim.x + threadIdx.x;
    if (e < E_) atomicAdd(&deg[ei[E_ + e]], 1);
}

// Block-wise exclusive scan: 256 threads x 4 elems = 1024 per block.
__global__ void scan_blocks_kernel(const int* __restrict__ deg, int* __restrict__ rowptr,
                                   int* __restrict__ part, int n) {
    __shared__ int sd[256];
    const int tid = threadIdx.x;
    const int base = blockIdx.x * 1024 + tid * 4;
    int v[4];
#pragma unroll
    for (int i = 0; i < 4; i++) {
        int idx = base + i;
        v[i] = (idx < n) ? deg[idx] : 0;
    }
    int s = v[0] + v[1] + v[2] + v[3];
    sd[tid] = s;
    __syncthreads();
    for (int off = 1; off < 256; off <<= 1) {
        int x = (tid >= off) ? sd[tid - off] : 0;
        __syncthreads();
        sd[tid] += x;
        __syncthreads();
    }
    int incl = sd[tid];
    int run = incl - s;
#pragma unroll
    for (int i = 0; i < 4; i++) {
        int idx = base + i;
        if (idx < n) rowptr[idx] = run;
        run += v[i];
    }
    if (tid == 0) part[blockIdx.x] = sd[255];
}

__global__ void scan_part_kernel(int* __restrict__ part, int nb) {
    __shared__ int sd[128];
    const int tid = threadIdx.x;
    int v = (tid < nb) ? part[tid] : 0;
    sd[tid] = v;
    __syncthreads();
    for (int off = 1; off < 128; off <<= 1) {
        int x = (tid >= off) ? sd[tid - off] : 0;
        __syncthreads();
        sd[tid] += x;
        __syncthreads();
    }
    if (tid < nb) part[tid] = sd[tid] - v;
}

__global__ void add_offsets_kernel(int* __restrict__ rowptr, int* __restrict__ cursor,
                                   const int* __restrict__ part, int n, int E_) {
    int idx = blockIdx.x * blockDim.x + threadIdx.x;
    if (idx < n) {
        int r = rowptr[idx] + part[idx >> 10];
        rowptr[idx] = r;
        cursor[idx] = r;
    }
    if (idx == 0) rowptr[n] = E_;
}

__global__ void fill_kernel(const int* __restrict__ ei, int* __restrict__ cursor,
                            int* __restrict__ col, int E_) {
    int e = blockIdx.x * blockDim.x + threadIdx.x;
    if (e < E_) {
        int d = ei[E_ + e];
        int pos = atomicAdd(&cursor[d], 1);
        col[pos] = ei[e];
    }
}

// ---------------------------------------------------------------------------
// proj128: y[n,64] = x[n,128] @ w[128,64]   (no bias, no relu)
// 64 nodes/block, 256 threads, LDS tile stride 130 (2-way bank alias = free).
// ---------------------------------------------------------------------------
__global__ __launch_bounds__(256) void proj128_kernel(
    const float* __restrict__ x, float* __restrict__ y,
    const float* __restrict__ w, int n) {
    constexpr int F = 128, STR = F + 2;
    __shared__ float xs[64 * STR];
    const int tid = threadIdx.x;
    const int tile = blockIdx.x;
    // stage 64 rows x 128 floats (float2, coalesced)
    for (int idx = tid; idx < 64 * (F / 2); idx += 256) {
        int r = idx >> 6;   // F/2 == 64
        int c = idx & 63;
        int node = tile * 64 + r;
        float2 v = make_float2(0.f, 0.f);
        if (node < n) v = *reinterpret_cast<const float2*>(x + (size_t)node * F + c * 2);
        *reinterpret_cast<float2*>(&xs[r * STR + c * 2]) = v;
    }
    __syncthreads();
    const int lane = tid & 63;
    const int j0 = __builtin_amdgcn_readfirstlane(tid >> 6) << 4;
    float a[16];
#pragma unroll
    for (int jj = 0; jj < 16; jj++) a[jj] = 0.f;
    for (int k = 0; k < F; k++) {
        const float zk = xs[lane * STR + k];
#pragma unroll
        for (int jj = 0; jj < 16; jj++) a[jj] = fmaf(zk, w[k * 64 + j0 + jj], a[jj]);
    }
    const int node = tile * 64 + lane;
    if (node < n) {
        float* orow = y + (size_t)node * 64 + j0;
#pragma unroll
        for (int jj = 0; jj < 16; jj += 4) {
            *reinterpret_cast<float4*>(orow + jj) =
                make_float4(a[jj], a[jj + 1], a[jj + 2], a[jj + 3]);
        }
    }
}

// ---------------------------------------------------------------------------
// gather64: t[node] = relu(y[node] + sum_nbr y[nbr] + b)
// One wave per node, lane = feature (64-wide). No divergence inside a wave;
// col[] indices are wave-uniform -> scalar loads; 8 row loads in flight.
// ---------------------------------------------------------------------------
__global__ __launch_bounds__(256) void gather64_kernel(
    const float* __restrict__ y, float* __restrict__ t,
    const int* __restrict__ rowptr, const int* __restrict__ col,
    const float* __restrict__ bias, int n) {
    const int lane = threadIdx.x & 63;
    int node = __builtin_amdgcn_readfirstlane((blockIdx.x * 256 + threadIdx.x) >> 6);
    if (node >= n) return;
    float acc = y[(size_t)node * 64 + lane];
    const int rs = rowptr[node];
    const int re = rowptr[node + 1];
    int p = rs;
    for (; p + 8 <= re; p += 8) {
        int c0 = col[p + 0], c1 = col[p + 1], c2 = col[p + 2], c3 = col[p + 3];
        int c4 = col[p + 4], c5 = col[p + 5], c6 = col[p + 6], c7 = col[p + 7];
        float v0 = y[(size_t)c0 * 64 + lane];
        float v1 = y[(size_t)c1 * 64 + lane];
        float v2 = y[(size_t)c2 * 64 + lane];
        float v3 = y[(size_t)c3 * 64 + lane];
        float v4 = y[(size_t)c4 * 64 + lane];
        float v5 = y[(size_t)c5 * 64 + lane];
        float v6 = y[(size_t)c6 * 64 + lane];
        float v7 = y[(size_t)c7 * 64 + lane];
        acc += v0; acc += v1; acc += v2; acc += v3;
        acc += v4; acc += v5; acc += v6; acc += v7;
    }
    for (; p < re; ++p) acc += y[(size_t)col[p] * 64 + lane];
    t[(size_t)node * 64 + lane] = fmaxf(acc + bias[lane], 0.f);
}

// ---------------------------------------------------------------------------
// dual_gemv: u = relu(t @ w2 + b2); [optional] yout = u @ w1n; [optional] hout = u
// 64 nodes/block, 256 threads. Single LDS tile reused (overlay via barrier).
// ---------------------------------------------------------------------------
template <bool DO_SECOND, bool WRITE_H>
__global__ __launch_bounds__(256) void dual_gemv_kernel(
    const float* __restrict__ tin,
    const float* __restrict__ w2, const float* __restrict__ b2,
    const float* __restrict__ w1n,
    float* __restrict__ yout, float* __restrict__ hout, int n) {
    constexpr int STR = 66;
    __shared__ float s1[64 * STR];
    const int tid = threadIdx.x;
    const int tile = blockIdx.x;
    // stage 64 rows x 64 floats (float2)
    for (int idx = tid; idx < 64 * 32; idx += 256) {
        int r = idx >> 5;
        int c = idx & 31;
        int node = tile * 64 + r;
        float2 v = make_float2(0.f, 0.f);
        if (node < n) v = *reinterpret_cast<const float2*>(tin + (size_t)node * 64 + c * 2);
        *reinterpret_cast<float2*>(&s1[r * STR + c * 2]) = v;
    }
    __syncthreads();
    const int lane = tid & 63;
    const int j0 = __builtin_amdgcn_readfirstlane(tid >> 6) << 4;
    const int node = tile * 64 + lane;
    float a[16];
#pragma unroll
    for (int jj = 0; jj < 16; jj++) a[jj] = b2[j0 + jj];
    for (int k = 0; k < 64; k++) {
        const float tk = s1[lane * STR + k];
#pragma unroll
        for (int jj = 0; jj < 16; jj++) a[jj] = fmaf(tk, w2[k * 64 + j0 + jj], a[jj]);
    }
#pragma unroll
    for (int jj = 0; jj < 16; jj++) a[jj] = fmaxf(a[jj], 0.f);
    if (WRITE_H && node < n) {
        float* orow = hout + (size_t)node * 64 + j0;
#pragma unroll
        for (int jj = 0; jj < 16; jj += 4) {
            *reinterpret_cast<float4*>(orow + jj) =
                make_float4(a[jj], a[jj + 1], a[jj + 2], a[jj + 3]);
        }
    }
    if (DO_SECOND) {
        __syncthreads();  // all reads of s1 done
#pragma unroll
        for (int jj = 0; jj < 16; jj++) s1[lane * STR + j0 + jj] = a[jj];
        __syncthreads();
        float a2[16];
#pragma unroll
        for (int jj = 0; jj < 16; jj++) a2[jj] = 0.f;
        for (int k = 0; k < 64; k++) {
            const float uk = s1[lane * STR + k];
#pragma unroll
            for (int jj = 0; jj < 16; jj++) a2[jj] = fmaf(uk, w1n[k * 64 + j0 + jj], a2[jj]);
        }
        if (node < n) {
            float* orow = yout + (size_t)node * 64 + j0;
#pragma unroll
            for (int jj = 0; jj < 16; jj += 4) {
                *reinterpret_cast<float4*>(orow + jj) =
                    make_float4(a2[jj], a2[jj + 1], a2[jj + 2], a2[jj + 3]);
            }
        }
    }
}

// ---------------------------------------------------------------------------
// Mean-pool per graph (batch sorted) + 2-layer head. One block per graph.
// ---------------------------------------------------------------------------
__global__ __launch_bounds__(256) void pool_head_kernel(
    const float* __restrict__ h, const int* __restrict__ batch,
    const float* __restrict__ l1w, const float* __restrict__ l1b,
    const float* __restrict__ l2w, const float* __restrict__ l2b,
    float* __restrict__ out, int n) {
    const int g = blockIdx.x;
    const int tid = threadIdx.x;
    auto lb = [&](int key) {
        int lo = 0, hi = n;
        while (lo < hi) {
            int mid = (lo + hi) >> 1;
            if (batch[mid] < key) lo = mid + 1;
            else hi = mid;
        }
        return lo;
    };
    const int lo = lb(g), hi = lb(g + 1);
    const int cnt = hi - lo;

    const int f = tid & 63;
    const int part = tid >> 6;
    float s = 0.f;
    for (int i = lo + part; i < hi; i += 4) s += h[(size_t)i * 64 + f];

    __shared__ float red[256];
    __shared__ float pooled[64];
    __shared__ float r[64];
    red[tid] = s;
    __syncthreads();
    if (tid < 64) {
        float v = red[tid] + red[tid + 64] + red[tid + 128] + red[tid + 192];
        pooled[tid] = v / (float)((cnt > 1) ? cnt : 1);
    }
    __syncthreads();
    if (tid < 64) {
        float a = l1b[tid];
        for (int k = 0; k < 64; k++) a = fmaf(pooled[k], l1w[k * 64 + tid], a);
        r[tid] = fmaxf(a, 0.f);
    }
    __syncthreads();
    if (tid < 2) {
        float a = l2b[tid];
        for (int k = 0; k < 64; k++) a = fmaf(r[k], l2w[k * 2 + tid], a);
        out[g * 2 + tid] = a;
    }
}

// ---------------------------------------------------------------------------

extern "C" void kernel_launch(void* const* d_in, const int* in_sizes, int n_in,
                              void* d_out, int out_size, void* d_ws, size_t ws_size,
                              hipStream_t stream) {
    const float* x    = (const float*)d_in[0];
    const int* ei     = (const int*)d_in[1];
    const int* batch  = (const int*)d_in[2];
    const float* l0w1 = (const float*)d_in[3];
    const float* l0b1 = (const float*)d_in[4];
    const float* l0w2 = (const float*)d_in[5];
    const float* l0b2 = (const float*)d_in[6];
    const float* l1w1 = (const float*)d_in[7];
    const float* l1b1 = (const float*)d_in[8];
    const float* l1w2 = (const float*)d_in[9];
    const float* l1b2 = (const float*)d_in[10];
    const float* l2w1 = (const float*)d_in[11];
    const float* l2b1 = (const float*)d_in[12];
    const float* l2w2 = (const float*)d_in[13];
    const float* l2b2 = (const float*)d_in[14];
    const float* lin1w = (const float*)d_in[15];
    const float* lin1b = (const float*)d_in[16];
    const float* lin2w = (const float*)d_in[17];
    const float* lin2b = (const float*)d_in[18];
    float* out = (float*)d_out;

    const int N  = in_sizes[2];
    const int E_ = in_sizes[1] / 2;

    char* ws = (char*)d_ws;
    size_t off = 0;
    auto alloc = [&](size_t bytes) {
        void* p = ws + off;
        off += (bytes + 255) & ~(size_t)255;
        return p;
    };
    int* rowptr  = (int*)alloc((size_t)(N + 1) * 4);
    int* degcur  = (int*)alloc((size_t)N * 4);
    int* part    = (int*)alloc(128 * 4);
    int* col     = (int*)alloc((size_t)E_ * 4);
    float* bufA  = (float*)alloc((size_t)N * 64 * 4);
    float* bufB  = (float*)alloc((size_t)N * 64 * 4);
    (void)ws_size;

    const int NB = (N + 1023) / 1024;

    // --- CSR build ---
    zero_int_kernel<<<(N + 255) / 256, 256, 0, stream>>>(degcur, N);
    hist_kernel<<<(E_ + 255) / 256, 256, 0, stream>>>(ei, degcur, E_);
    scan_blocks_kernel<<<NB, 256, 0, stream>>>(degcur, rowptr, part, N);
    scan_part_kernel<<<1, 128, 0, stream>>>(part, NB);
    add_offsets_kernel<<<(N + 255) / 256, 256, 0, stream>>>(rowptr, degcur, part, N, E_);
    fill_kernel<<<(E_ + 255) / 256, 256, 0, stream>>>(ei, degcur, col, E_);

    const int ntiles = (N + 63) / 64;
    const int gblocks = (N + 3) / 4;  // 4 nodes (waves) per 256-thread block

    // layer 0
    proj128_kernel<<<ntiles, 256, 0, stream>>>(x, bufA, l0w1, N);
    gather64_kernel<<<gblocks, 256, 0, stream>>>(bufA, bufB, rowptr, col, l0b1, N);
    dual_gemv_kernel<true, false><<<ntiles, 256, 0, stream>>>(
        bufB, l0w2, l0b2, l1w1, bufA, nullptr, N);
    // layer 1
    gather64_kernel<<<gblocks, 256, 0, stream>>>(bufA, bufB, rowptr, col, l1b1, N);
    dual_gemv_kernel<true, false><<<ntiles, 256, 0, stream>>>(
        bufB, l1w2, l1b2, l2w1, bufA, nullptr, N);
    // layer 2
    gather64_kernel<<<gblocks, 256, 0, stream>>>(bufA, bufB, rowptr, col, l2b1, N);
    dual_gemv_kernel<false, true><<<ntiles, 256, 0, stream>>>(
        bufB, l2w2, l2b2, nullptr, nullptr, bufB, N);

    // --- pool + head ---
    pool_head_kernel<<<64, 256, 0, stream>>>(bufB, batch, lin1w, lin1b, lin2w, lin2b, out, N);
}

// Round 3
// 468.538 us; speedup vs baseline: 1.4474x; 1.2857x over previous
//
#include <hip/hip_runtime.h>
#include <hip/hip_bf16.h>

// ---------------------------------------------------------------------------
// GIN model, proj-first formulation:
//   per layer: y = h @ w1  (linearity: aggregate AFTER projecting, 64-wide)
//              t = relu(y_self + sum_nbr y + b1)
//              h' = relu(t @ w2 + b2)           (fused with next layer's proj)
// CSR built per call via bucketed counting sort (L2-friendly scatter).
// fp32 throughout.
// ---------------------------------------------------------------------------

// Buckets: 512 nodes per bucket (shift 9). K = ceil(N/512) <= 1024 supported.
// Packed edge: (dst & 511) << 22 | src   (requires src < 2^22).

__global__ __launch_bounds__(1024) void zero1024_kernel(int* __restrict__ p) {
    p[threadIdx.x] = 0;
}

__global__ __launch_bounds__(256) void count_buckets_kernel(
    const int* __restrict__ ei, int* __restrict__ gcount, int E_) {
    __shared__ int hist[1024];
    const int tid = threadIdx.x;
    for (int i = tid; i < 1024; i += 256) hist[i] = 0;
    __syncthreads();
    const int base = blockIdx.x * 2048;
#pragma unroll
    for (int i = 0; i < 8; i++) {
        int e = base + i * 256 + tid;
        if (e < E_) atomicAdd(&hist[ei[E_ + e] >> 9], 1);
    }
    __syncthreads();
    for (int i = tid; i < 1024; i += 256)
        if (hist[i]) atomicAdd(&gcount[i], hist[i]);
}

__global__ __launch_bounds__(1024) void scan_buckets_kernel(
    const int* __restrict__ gcount, int* __restrict__ bbase,
    int* __restrict__ gcursor, int* __restrict__ rowptr, int K, int E_, int n) {
    __shared__ int sd[1024];
    const int tid = threadIdx.x;
    int v = (tid < K) ? gcount[tid] : 0;
    sd[tid] = v;
    __syncthreads();
    for (int off = 1; off < 1024; off <<= 1) {
        int x = (tid >= off) ? sd[tid - off] : 0;
        __syncthreads();
        sd[tid] += x;
        __syncthreads();
    }
    if (tid < K) {
        int excl = sd[tid] - v;
        bbase[tid] = excl;
        gcursor[tid] = excl;
    }
    if (tid == 0) {
        bbase[K] = E_;
        rowptr[n] = E_;
    }
}

__global__ __launch_bounds__(256) void bucketize_kernel(
    const int* __restrict__ ei, int* __restrict__ gcursor,
    unsigned* __restrict__ bpack, int E_) {
    __shared__ int hist[1024];
    __shared__ int gbase[1024];
    const int tid = threadIdx.x;
    for (int i = tid; i < 1024; i += 256) hist[i] = 0;
    __syncthreads();
    const int base = blockIdx.x * 2048;
    int bkt[8], rnk[8];
    unsigned pk[8];
#pragma unroll
    for (int i = 0; i < 8; i++) {
        int e = base + i * 256 + tid;
        bkt[i] = -1;
        if (e < E_) {
            int s = ei[e];
            int d = ei[E_ + e];
            bkt[i] = d >> 9;
            pk[i] = (unsigned)s | ((unsigned)(d & 511) << 22);
            rnk[i] = atomicAdd(&hist[bkt[i]], 1);
        }
    }
    __syncthreads();
    for (int i = tid; i < 1024; i += 256)
        if (hist[i]) gbase[i] = atomicAdd(&gcursor[i], hist[i]);
    __syncthreads();
#pragma unroll
    for (int i = 0; i < 8; i++)
        if (bkt[i] >= 0) bpack[gbase[bkt[i]] + rnk[i]] = pk[i];
}

// One block per bucket: LDS count + scan -> rowptr slice, then LDS-cursor
// scatter of col into the bucket's contiguous region (L2-dense writes).
__global__ __launch_bounds__(256) void build_csr_kernel(
    const unsigned* __restrict__ bpack, const int* __restrict__ bbase,
    int* __restrict__ rowptr, int* __restrict__ col, int n) {
    __shared__ int cnt[512];
    __shared__ int sp[256];
    const int tid = threadIdx.x;
    const int b = blockIdx.x;
    const int nstart = b << 9;
    const int estart = bbase[b];
    const int eend = bbase[b + 1];
    cnt[tid] = 0;
    cnt[tid + 256] = 0;
    __syncthreads();
    for (int e = estart + tid; e < eend; e += 256)
        atomicAdd(&cnt[bpack[e] >> 22], 1);
    __syncthreads();
    const int v0 = cnt[tid * 2], v1 = cnt[tid * 2 + 1];
    const int s = v0 + v1;
    sp[tid] = s;
    __syncthreads();
    for (int off = 1; off < 256; off <<= 1) {
        int x = (tid >= off) ? sp[tid - off] : 0;
        __syncthreads();
        sp[tid] += x;
        __syncthreads();
    }
    const int excl = sp[tid] - s;
    cnt[tid * 2] = excl;
    cnt[tid * 2 + 1] = excl + v0;
    const int node0 = nstart + tid * 2;
    if (node0 < n) rowptr[node0] = estart + excl;
    if (node0 + 1 < n) rowptr[node0 + 1] = estart + excl + v0;
    __syncthreads();
    for (int e = estart + tid; e < eend; e += 256) {
        unsigned p = bpack[e];
        int pos = estart + atomicAdd(&cnt[p >> 22], 1);
        col[pos] = (int)(p & 0x3FFFFFu);
    }
}

// ---------------------------------------------------------------------------
// proj128: y[n,64] = x[n,128] @ w[128,64]   (no bias, no relu)
// ---------------------------------------------------------------------------
__global__ __launch_bounds__(256) void proj128_kernel(
    const float* __restrict__ x, float* __restrict__ y,
    const float* __restrict__ w, int n) {
    constexpr int F = 128, STR = F + 2;
    __shared__ float xs[64 * STR];
    const int tid = threadIdx.x;
    const int tile = blockIdx.x;
    for (int idx = tid; idx < 64 * (F / 2); idx += 256) {
        int r = idx >> 6;
        int c = idx & 63;
        int node = tile * 64 + r;
        float2 v = make_float2(0.f, 0.f);
        if (node < n) v = *reinterpret_cast<const float2*>(x + (size_t)node * F + c * 2);
        *reinterpret_cast<float2*>(&xs[r * STR + c * 2]) = v;
    }
    __syncthreads();
    const int lane = tid & 63;
    const int j0 = __builtin_amdgcn_readfirstlane(tid >> 6) << 4;
    float a[16];
#pragma unroll
    for (int jj = 0; jj < 16; jj++) a[jj] = 0.f;
    for (int k = 0; k < F; k++) {
        const float zk = xs[lane * STR + k];
#pragma unroll
        for (int jj = 0; jj < 16; jj++) a[jj] = fmaf(zk, w[k * 64 + j0 + jj], a[jj]);
    }
    const int node = tile * 64 + lane;
    if (node < n) {
        float* orow = y + (size_t)node * 64 + j0;
#pragma unroll
        for (int jj = 0; jj < 16; jj += 4) {
            *reinterpret_cast<float4*>(orow + jj) =
                make_float4(a[jj], a[jj + 1], a[jj + 2], a[jj + 3]);
        }
    }
}

// ---------------------------------------------------------------------------
// gather64: t[node] = relu(y[node] + sum_nbr y[nbr] + b)
// One wave per node, lane = feature; col indices wave-uniform (scalar loads).
// ---------------------------------------------------------------------------
__global__ __launch_bounds__(256) void gather64_kernel(
    const float* __restrict__ y, float* __restrict__ t,
    const int* __restrict__ rowptr, const int* __restrict__ col,
    const float* __restrict__ bias, int n) {
    const int lane = threadIdx.x & 63;
    int node = __builtin_amdgcn_readfirstlane((blockIdx.x * 256 + threadIdx.x) >> 6);
    if (node >= n) return;
    float acc = y[(size_t)node * 64 + lane];
    const int rs = rowptr[node];
    const int re = rowptr[node + 1];
    int p = rs;
    for (; p + 8 <= re; p += 8) {
        int c0 = col[p + 0], c1 = col[p + 1], c2 = col[p + 2], c3 = col[p + 3];
        int c4 = col[p + 4], c5 = col[p + 5], c6 = col[p + 6], c7 = col[p + 7];
        float v0 = y[(size_t)c0 * 64 + lane];
        float v1 = y[(size_t)c1 * 64 + lane];
        float v2 = y[(size_t)c2 * 64 + lane];
        float v3 = y[(size_t)c3 * 64 + lane];
        float v4 = y[(size_t)c4 * 64 + lane];
        float v5 = y[(size_t)c5 * 64 + lane];
        float v6 = y[(size_t)c6 * 64 + lane];
        float v7 = y[(size_t)c7 * 64 + lane];
        acc += v0; acc += v1; acc += v2; acc += v3;
        acc += v4; acc += v5; acc += v6; acc += v7;
    }
    for (; p < re; ++p) acc += y[(size_t)col[p] * 64 + lane];
    t[(size_t)node * 64 + lane] = fmaxf(acc + bias[lane], 0.f);
}

// ---------------------------------------------------------------------------
// dual_gemv: u = relu(t @ w2 + b2); [optional] yout = u @ w1n; [optional] hout = u
// ---------------------------------------------------------------------------
template <bool DO_SECOND, bool WRITE_H>
__global__ __launch_bounds__(256) void dual_gemv_kernel(
    const float* __restrict__ tin,
    const float* __restrict__ w2, const float* __restrict__ b2,
    const float* __restrict__ w1n,
    float* __restrict__ yout, float* __restrict__ hout, int n) {
    constexpr int STR = 66;
    __shared__ float s1[64 * STR];
    const int tid = threadIdx.x;
    const int tile = blockIdx.x;
    for (int idx = tid; idx < 64 * 32; idx += 256) {
        int r = idx >> 5;
        int c = idx & 31;
        int node = tile * 64 + r;
        float2 v = make_float2(0.f, 0.f);
        if (node < n) v = *reinterpret_cast<const float2*>(tin + (size_t)node * 64 + c * 2);
        *reinterpret_cast<float2*>(&s1[r * STR + c * 2]) = v;
    }
    __syncthreads();
    const int lane = tid & 63;
    const int j0 = __builtin_amdgcn_readfirstlane(tid >> 6) << 4;
    const int node = tile * 64 + lane;
    float a[16];
#pragma unroll
    for (int jj = 0; jj < 16; jj++) a[jj] = b2[j0 + jj];
    for (int k = 0; k < 64; k++) {
        const float tk = s1[lane * STR + k];
#pragma unroll
        for (int jj = 0; jj < 16; jj++) a[jj] = fmaf(tk, w2[k * 64 + j0 + jj], a[jj]);
    }
#pragma unroll
    for (int jj = 0; jj < 16; jj++) a[jj] = fmaxf(a[jj], 0.f);
    if (WRITE_H && node < n) {
        float* orow = hout + (size_t)node * 64 + j0;
#pragma unroll
        for (int jj = 0; jj < 16; jj += 4) {
            *reinterpret_cast<float4*>(orow + jj) =
                make_float4(a[jj], a[jj + 1], a[jj + 2], a[jj + 3]);
        }
    }
    if (DO_SECOND) {
        __syncthreads();
#pragma unroll
        for (int jj = 0; jj < 16; jj++) s1[lane * STR + j0 + jj] = a[jj];
        __syncthreads();
        float a2[16];
#pragma unroll
        for (int jj = 0; jj < 16; jj++) a2[jj] = 0.f;
        for (int k = 0; k < 64; k++) {
            const float uk = s1[lane * STR + k];
#pragma unroll
            for (int jj = 0; jj < 16; jj++) a2[jj] = fmaf(uk, w1n[k * 64 + j0 + jj], a2[jj]);
        }
        if (node < n) {
            float* orow = yout + (size_t)node * 64 + j0;
#pragma unroll
            for (int jj = 0; jj < 16; jj += 4) {
                *reinterpret_cast<float4*>(orow + jj) =
                    make_float4(a2[jj], a2[jj + 1], a2[jj + 2], a2[jj + 3]);
            }
        }
    }
}

// ---------------------------------------------------------------------------
// Mean-pool per graph (batch sorted) + 2-layer head. One block per graph.
// ---------------------------------------------------------------------------
__global__ __launch_bounds__(256) void pool_head_kernel(
    const float* __restrict__ h, const int* __restrict__ batch,
    const float* __restrict__ l1w, const float* __restrict__ l1b,
    const float* __restrict__ l2w, const float* __restrict__ l2b,
    float* __restrict__ out, int n) {
    const int g = blockIdx.x;
    const int tid = threadIdx.x;
    auto lb = [&](int key) {
        int lo = 0, hi = n;
        while (lo < hi) {
            int mid = (lo + hi) >> 1;
            if (batch[mid] < key) lo = mid + 1;
            else hi = mid;
        }
        return lo;
    };
    const int lo = lb(g), hi = lb(g + 1);
    const int cnt = hi - lo;

    const int f = tid & 63;
    const int part = tid >> 6;
    float s = 0.f;
    for (int i = lo + part; i < hi; i += 4) s += h[(size_t)i * 64 + f];

    __shared__ float red[256];
    __shared__ float pooled[64];
    __shared__ float r[64];
    red[tid] = s;
    __syncthreads();
    if (tid < 64) {
        float v = red[tid] + red[tid + 64] + red[tid + 128] + red[tid + 192];
        pooled[tid] = v / (float)((cnt > 1) ? cnt : 1);
    }
    __syncthreads();
    if (tid < 64) {
        float a = l1b[tid];
        for (int k = 0; k < 64; k++) a = fmaf(pooled[k], l1w[k * 64 + tid], a);
        r[tid] = fmaxf(a, 0.f);
    }
    __syncthreads();
    if (tid < 2) {
        float a = l2b[tid];
        for (int k = 0; k < 64; k++) a = fmaf(r[k], l2w[k * 2 + tid], a);
        out[g * 2 + tid] = a;
    }
}

// ---------------------------------------------------------------------------

extern "C" void kernel_launch(void* const* d_in, const int* in_sizes, int n_in,
                              void* d_out, int out_size, void* d_ws, size_t ws_size,
                              hipStream_t stream) {
    const float* x    = (const float*)d_in[0];
    const int* ei     = (const int*)d_in[1];
    const int* batch  = (const int*)d_in[2];
    const float* l0w1 = (const float*)d_in[3];
    const float* l0b1 = (const float*)d_in[4];
    const float* l0w2 = (const float*)d_in[5];
    const float* l0b2 = (const float*)d_in[6];
    const float* l1w1 = (const float*)d_in[7];
    const float* l1b1 = (const float*)d_in[8];
    const float* l1w2 = (const float*)d_in[9];
    const float* l1b2 = (const float*)d_in[10];
    const float* l2w1 = (const float*)d_in[11];
    const float* l2b1 = (const float*)d_in[12];
    const float* l2w2 = (const float*)d_in[13];
    const float* l2b2 = (const float*)d_in[14];
    const float* lin1w = (const float*)d_in[15];
    const float* lin1b = (const float*)d_in[16];
    const float* lin2w = (const float*)d_in[17];
    const float* lin2b = (const float*)d_in[18];
    float* out = (float*)d_out;

    const int N  = in_sizes[2];
    const int E_ = in_sizes[1] / 2;
    const int K  = (N + 511) >> 9;   // buckets of 512 nodes (K <= 1024)

    char* ws = (char*)d_ws;
    size_t off = 0;
    auto alloc = [&](size_t bytes) {
        void* p = ws + off;
        off += (bytes + 255) & ~(size_t)255;
        return p;
    };
    int* rowptr  = (int*)alloc((size_t)(N + 1) * 4);
    int* col     = (int*)alloc((size_t)E_ * 4);
    int* gcount  = (int*)alloc(1024 * 4);
    int* bbase   = (int*)alloc(1025 * 4);
    int* gcursor = (int*)alloc(1024 * 4);
    float* bufA  = (float*)alloc((size_t)N * 64 * 4);
    float* bufB  = (float*)alloc((size_t)N * 64 * 4);
    unsigned* bpack = (unsigned*)bufA;  // alias: bpack dead before proj writes bufA
    (void)ws_size;

    const int nch = (E_ + 2047) / 2048;

    // --- CSR build (bucketed counting sort) ---
    zero1024_kernel<<<1, 1024, 0, stream>>>(gcount);
    count_buckets_kernel<<<nch, 256, 0, stream>>>(ei, gcount, E_);
    scan_buckets_kernel<<<1, 1024, 0, stream>>>(gcount, bbase, gcursor, rowptr, K, E_, N);
    bucketize_kernel<<<nch, 256, 0, stream>>>(ei, gcursor, bpack, E_);
    build_csr_kernel<<<K, 256, 0, stream>>>(bpack, bbase, rowptr, col, N);

    const int ntiles = (N + 63) / 64;
    const int gblocks = (N + 3) / 4;

    // layer 0
    proj128_kernel<<<ntiles, 256, 0, stream>>>(x, bufA, l0w1, N);
    gather64_kernel<<<gblocks, 256, 0, stream>>>(bufA, bufB, rowptr, col, l0b1, N);
    dual_gemv_kernel<true, false><<<ntiles, 256, 0, stream>>>(
        bufB, l0w2, l0b2, l1w1, bufA, nullptr, N);
    // layer 1
    gather64_kernel<<<gblocks, 256, 0, stream>>>(bufA, bufB, rowptr, col, l1b1, N);
    dual_gemv_kernel<true, false><<<ntiles, 256, 0, stream>>>(
        bufB, l1w2, l1b2, l2w1, bufA, nullptr, N);
    // layer 2
    gather64_kernel<<<gblocks, 256, 0, stream>>>(bufA, bufB, rowptr, col, l2b1, N);
    dual_gemv_kernel<false, true><<<ntiles, 256, 0, stream>>>(
        bufB, l2w2, l2b2, nullptr, nullptr, bufB, N);

    // --- pool + head ---
    pool_head_kernel<<<64, 256, 0, stream>>>(bufB, batch, lin1w, lin1b, lin2w, lin2b, out, N);
}

// Round 4
// 388.373 us; speedup vs baseline: 1.7462x; 1.2064x over previous
//
#include <hip/hip_runtime.h>
#include <hip/hip_bf16.h>

// ---------------------------------------------------------------------------
// GIN model, proj-first formulation:
//   per layer: y = h @ w1  (linearity: aggregate AFTER projecting, 64-wide)
//              t = relu(y_self + sum_nbr y + b1)
//              h' = relu(t @ w2 + b2)           (fused with next layer's proj)
// CSR built per call via bucketed counting sort (L2-friendly scatter).
// Pool: two-stage deterministic partial reduction (G*16 blocks) + head MLP.
// fp32 throughout.
// ---------------------------------------------------------------------------

__global__ __launch_bounds__(1024) void zero1024_kernel(int* __restrict__ p) {
    p[threadIdx.x] = 0;
}

__global__ __launch_bounds__(256) void count_buckets_kernel(
    const int* __restrict__ ei, int* __restrict__ gcount, int E_) {
    __shared__ int hist[1024];
    const int tid = threadIdx.x;
    for (int i = tid; i < 1024; i += 256) hist[i] = 0;
    __syncthreads();
    const int base = blockIdx.x * 2048;
#pragma unroll
    for (int i = 0; i < 8; i++) {
        int e = base + i * 256 + tid;
        if (e < E_) atomicAdd(&hist[ei[E_ + e] >> 9], 1);
    }
    __syncthreads();
    for (int i = tid; i < 1024; i += 256)
        if (hist[i]) atomicAdd(&gcount[i], hist[i]);
}

__global__ __launch_bounds__(1024) void scan_buckets_kernel(
    const int* __restrict__ gcount, int* __restrict__ bbase,
    int* __restrict__ gcursor, int* __restrict__ rowptr, int K, int E_, int n) {
    __shared__ int sd[1024];
    const int tid = threadIdx.x;
    int v = (tid < K) ? gcount[tid] : 0;
    sd[tid] = v;
    __syncthreads();
    for (int off = 1; off < 1024; off <<= 1) {
        int x = (tid >= off) ? sd[tid - off] : 0;
        __syncthreads();
        sd[tid] += x;
        __syncthreads();
    }
    if (tid < K) {
        int excl = sd[tid] - v;
        bbase[tid] = excl;
        gcursor[tid] = excl;
    }
    if (tid == 0) {
        bbase[K] = E_;
        rowptr[n] = E_;
    }
}

__global__ __launch_bounds__(256) void bucketize_kernel(
    const int* __restrict__ ei, int* __restrict__ gcursor,
    unsigned* __restrict__ bpack, int E_) {
    __shared__ int hist[1024];
    __shared__ int gbase[1024];
    const int tid = threadIdx.x;
    for (int i = tid; i < 1024; i += 256) hist[i] = 0;
    __syncthreads();
    const int base = blockIdx.x * 2048;
    int bkt[8], rnk[8];
    unsigned pk[8];
#pragma unroll
    for (int i = 0; i < 8; i++) {
        int e = base + i * 256 + tid;
        bkt[i] = -1;
        if (e < E_) {
            int s = ei[e];
            int d = ei[E_ + e];
            bkt[i] = d >> 9;
            pk[i] = (unsigned)s | ((unsigned)(d & 511) << 22);
            rnk[i] = atomicAdd(&hist[bkt[i]], 1);
        }
    }
    __syncthreads();
    for (int i = tid; i < 1024; i += 256)
        if (hist[i]) gbase[i] = atomicAdd(&gcursor[i], hist[i]);
    __syncthreads();
#pragma unroll
    for (int i = 0; i < 8; i++)
        if (bkt[i] >= 0) bpack[gbase[bkt[i]] + rnk[i]] = pk[i];
}

__global__ __launch_bounds__(256) void build_csr_kernel(
    const unsigned* __restrict__ bpack, const int* __restrict__ bbase,
    int* __restrict__ rowptr, int* __restrict__ col, int n) {
    __shared__ int cnt[512];
    __shared__ int sp[256];
    const int tid = threadIdx.x;
    const int b = blockIdx.x;
    const int nstart = b << 9;
    const int estart = bbase[b];
    const int eend = bbase[b + 1];
    cnt[tid] = 0;
    cnt[tid + 256] = 0;
    __syncthreads();
    for (int e = estart + tid; e < eend; e += 256)
        atomicAdd(&cnt[bpack[e] >> 22], 1);
    __syncthreads();
    const int v0 = cnt[tid * 2], v1 = cnt[tid * 2 + 1];
    const int s = v0 + v1;
    sp[tid] = s;
    __syncthreads();
    for (int off = 1; off < 256; off <<= 1) {
        int x = (tid >= off) ? sp[tid - off] : 0;
        __syncthreads();
        sp[tid] += x;
        __syncthreads();
    }
    const int excl = sp[tid] - s;
    cnt[tid * 2] = excl;
    cnt[tid * 2 + 1] = excl + v0;
    const int node0 = nstart + tid * 2;
    if (node0 < n) rowptr[node0] = estart + excl;
    if (node0 + 1 < n) rowptr[node0 + 1] = estart + excl + v0;
    __syncthreads();
    for (int e = estart + tid; e < eend; e += 256) {
        unsigned p = bpack[e];
        int pos = estart + atomicAdd(&cnt[p >> 22], 1);
        col[pos] = (int)(p & 0x3FFFFFu);
    }
}

// ---------------------------------------------------------------------------
// proj128: y[n,64] = x[n,128] @ w[128,64]
// ---------------------------------------------------------------------------
__global__ __launch_bounds__(256) void proj128_kernel(
    const float* __restrict__ x, float* __restrict__ y,
    const float* __restrict__ w, int n) {
    constexpr int F = 128, STR = F + 2;
    __shared__ float xs[64 * STR];
    const int tid = threadIdx.x;
    const int tile = blockIdx.x;
    for (int idx = tid; idx < 64 * (F / 2); idx += 256) {
        int r = idx >> 6;
        int c = idx & 63;
        int node = tile * 64 + r;
        float2 v = make_float2(0.f, 0.f);
        if (node < n) v = *reinterpret_cast<const float2*>(x + (size_t)node * F + c * 2);
        *reinterpret_cast<float2*>(&xs[r * STR + c * 2]) = v;
    }
    __syncthreads();
    const int lane = tid & 63;
    const int j0 = __builtin_amdgcn_readfirstlane(tid >> 6) << 4;
    float a[16];
#pragma unroll
    for (int jj = 0; jj < 16; jj++) a[jj] = 0.f;
    for (int k = 0; k < F; k++) {
        const float zk = xs[lane * STR + k];
#pragma unroll
        for (int jj = 0; jj < 16; jj++) a[jj] = fmaf(zk, w[k * 64 + j0 + jj], a[jj]);
    }
    const int node = tile * 64 + lane;
    if (node < n) {
        float* orow = y + (size_t)node * 64 + j0;
#pragma unroll
        for (int jj = 0; jj < 16; jj += 4) {
            *reinterpret_cast<float4*>(orow + jj) =
                make_float4(a[jj], a[jj + 1], a[jj + 2], a[jj + 3]);
        }
    }
}

// ---------------------------------------------------------------------------
// gather64: t[node] = relu(y[node] + sum_nbr y[nbr] + b)
// ---------------------------------------------------------------------------
__global__ __launch_bounds__(256) void gather64_kernel(
    const float* __restrict__ y, float* __restrict__ t,
    const int* __restrict__ rowptr, const int* __restrict__ col,
    const float* __restrict__ bias, int n) {
    const int lane = threadIdx.x & 63;
    int node = __builtin_amdgcn_readfirstlane((blockIdx.x * 256 + threadIdx.x) >> 6);
    if (node >= n) return;
    float acc = y[(size_t)node * 64 + lane];
    const int rs = rowptr[node];
    const int re = rowptr[node + 1];
    int p = rs;
    for (; p + 8 <= re; p += 8) {
        int c0 = col[p + 0], c1 = col[p + 1], c2 = col[p + 2], c3 = col[p + 3];
        int c4 = col[p + 4], c5 = col[p + 5], c6 = col[p + 6], c7 = col[p + 7];
        float v0 = y[(size_t)c0 * 64 + lane];
        float v1 = y[(size_t)c1 * 64 + lane];
        float v2 = y[(size_t)c2 * 64 + lane];
        float v3 = y[(size_t)c3 * 64 + lane];
        float v4 = y[(size_t)c4 * 64 + lane];
        float v5 = y[(size_t)c5 * 64 + lane];
        float v6 = y[(size_t)c6 * 64 + lane];
        float v7 = y[(size_t)c7 * 64 + lane];
        acc += v0; acc += v1; acc += v2; acc += v3;
        acc += v4; acc += v5; acc += v6; acc += v7;
    }
    for (; p < re; ++p) acc += y[(size_t)col[p] * 64 + lane];
    t[(size_t)node * 64 + lane] = fmaxf(acc + bias[lane], 0.f);
}

// ---------------------------------------------------------------------------
// dual_gemv: u = relu(t @ w2 + b2); [optional] yout = u @ w1n; [optional] hout = u
// ---------------------------------------------------------------------------
template <bool DO_SECOND, bool WRITE_H>
__global__ __launch_bounds__(256) void dual_gemv_kernel(
    const float* __restrict__ tin,
    const float* __restrict__ w2, const float* __restrict__ b2,
    const float* __restrict__ w1n,
    float* __restrict__ yout, float* __restrict__ hout, int n) {
    constexpr int STR = 66;
    __shared__ float s1[64 * STR];
    const int tid = threadIdx.x;
    const int tile = blockIdx.x;
    for (int idx = tid; idx < 64 * 32; idx += 256) {
        int r = idx >> 5;
        int c = idx & 31;
        int node = tile * 64 + r;
        float2 v = make_float2(0.f, 0.f);
        if (node < n) v = *reinterpret_cast<const float2*>(tin + (size_t)node * 64 + c * 2);
        *reinterpret_cast<float2*>(&s1[r * STR + c * 2]) = v;
    }
    __syncthreads();
    const int lane = tid & 63;
    const int j0 = __builtin_amdgcn_readfirstlane(tid >> 6) << 4;
    const int node = tile * 64 + lane;
    float a[16];
#pragma unroll
    for (int jj = 0; jj < 16; jj++) a[jj] = b2[j0 + jj];
    for (int k = 0; k < 64; k++) {
        const float tk = s1[lane * STR + k];
#pragma unroll
        for (int jj = 0; jj < 16; jj++) a[jj] = fmaf(tk, w2[k * 64 + j0 + jj], a[jj]);
    }
#pragma unroll
    for (int jj = 0; jj < 16; jj++) a[jj] = fmaxf(a[jj], 0.f);
    if (WRITE_H && node < n) {
        float* orow = hout + (size_t)node * 64 + j0;
#pragma unroll
        for (int jj = 0; jj < 16; jj += 4) {
            *reinterpret_cast<float4*>(orow + jj) =
                make_float4(a[jj], a[jj + 1], a[jj + 2], a[jj + 3]);
        }
    }
    if (DO_SECOND) {
        __syncthreads();
#pragma unroll
        for (int jj = 0; jj < 16; jj++) s1[lane * STR + j0 + jj] = a[jj];
        __syncthreads();
        float a2[16];
#pragma unroll
        for (int jj = 0; jj < 16; jj++) a2[jj] = 0.f;
        for (int k = 0; k < 64; k++) {
            const float uk = s1[lane * STR + k];
#pragma unroll
            for (int jj = 0; jj < 16; jj++) a2[jj] = fmaf(uk, w1n[k * 64 + j0 + jj], a2[jj]);
        }
        if (node < n) {
            float* orow = yout + (size_t)node * 64 + j0;
#pragma unroll
            for (int jj = 0; jj < 16; jj += 4) {
                *reinterpret_cast<float4*>(orow + jj) =
                    make_float4(a2[jj], a2[jj + 1], a2[jj + 2], a2[jj + 3]);
            }
        }
    }
}

// ---------------------------------------------------------------------------
// Pool stage 1: G*PARTS blocks; block (g,part) reduces a sub-range of graph g.
// Deterministic (fixed partition, no float atomics).
// ---------------------------------------------------------------------------
#define POOL_PARTS 16
__global__ __launch_bounds__(256) void pool_partial_kernel(
    const float* __restrict__ h, const int* __restrict__ batch,
    float* __restrict__ partials, int n) {
    const int g = blockIdx.x >> 4;        // / POOL_PARTS
    const int part = blockIdx.x & 15;
    const int tid = threadIdx.x;
    auto lb = [&](int key) {
        int lo = 0, hi = n;
        while (lo < hi) {
            int mid = (lo + hi) >> 1;
            if (batch[mid] < key) lo = mid + 1;
            else hi = mid;
        }
        return lo;
    };
    const int lo = lb(g), hi = lb(g + 1);
    const int cnt = hi - lo;
    const int s0 = lo + (int)(((long long)cnt * part) / POOL_PARTS);
    const int s1 = lo + (int)(((long long)cnt * (part + 1)) / POOL_PARTS);

    const int f = tid & 63;
    const int q = tid >> 6;
    float s = 0.f;
    for (int i = s0 + q; i < s1; i += 4) s += h[(size_t)i * 64 + f];

    __shared__ float red[256];
    red[tid] = s;
    __syncthreads();
    if (tid < 64) {
        partials[(size_t)blockIdx.x * 64 + tid] =
            red[tid] + red[tid + 64] + red[tid + 128] + red[tid + 192];
    }
}

// ---------------------------------------------------------------------------
// Pool stage 2 + head MLP. One block per graph; reads 16 partials.
// ---------------------------------------------------------------------------
__global__ __launch_bounds__(64) void pool_head_kernel(
    const float* __restrict__ partials, const int* __restrict__ batch,
    const float* __restrict__ l1w, const float* __restrict__ l1b,
    const float* __restrict__ l2w, const float* __restrict__ l2b,
    float* __restrict__ out, int n) {
    const int g = blockIdx.x;
    const int tid = threadIdx.x;
    auto lb = [&](int key) {
        int lo = 0, hi = n;
        while (lo < hi) {
            int mid = (lo + hi) >> 1;
            if (batch[mid] < key) lo = mid + 1;
            else hi = mid;
        }
        return lo;
    };
    const int cnt = lb(g + 1) - lb(g);

    __shared__ float pooled[64];
    __shared__ float r[64];
    float v = 0.f;
#pragma unroll
    for (int p = 0; p < POOL_PARTS; p++)
        v += partials[(size_t)(g * POOL_PARTS + p) * 64 + tid];
    pooled[tid] = v / (float)((cnt > 1) ? cnt : 1);
    __syncthreads();
    float a = l1b[tid];
    for (int k = 0; k < 64; k++) a = fmaf(pooled[k], l1w[k * 64 + tid], a);
    r[tid] = fmaxf(a, 0.f);
    __syncthreads();
    if (tid < 2) {
        float a2 = l2b[tid];
        for (int k = 0; k < 64; k++) a2 = fmaf(r[k], l2w[k * 2 + tid], a2);
        out[g * 2 + tid] = a2;
    }
}

// ---------------------------------------------------------------------------

extern "C" void kernel_launch(void* const* d_in, const int* in_sizes, int n_in,
                              void* d_out, int out_size, void* d_ws, size_t ws_size,
                              hipStream_t stream) {
    const float* x    = (const float*)d_in[0];
    const int* ei     = (const int*)d_in[1];
    const int* batch  = (const int*)d_in[2];
    const float* l0w1 = (const float*)d_in[3];
    const float* l0b1 = (const float*)d_in[4];
    const float* l0w2 = (const float*)d_in[5];
    const float* l0b2 = (const float*)d_in[6];
    const float* l1w1 = (const float*)d_in[7];
    const float* l1b1 = (const float*)d_in[8];
    const float* l1w2 = (const float*)d_in[9];
    const float* l1b2 = (const float*)d_in[10];
    const float* l2w1 = (const float*)d_in[11];
    const float* l2b1 = (const float*)d_in[12];
    const float* l2w2 = (const float*)d_in[13];
    const float* l2b2 = (const float*)d_in[14];
    const float* lin1w = (const float*)d_in[15];
    const float* lin1b = (const float*)d_in[16];
    const float* lin2w = (const float*)d_in[17];
    const float* lin2b = (const float*)d_in[18];
    float* out = (float*)d_out;

    const int N  = in_sizes[2];
    const int E_ = in_sizes[1] / 2;
    const int K  = (N + 511) >> 9;
    const int G  = out_size / 2;

    char* ws = (char*)d_ws;
    size_t off = 0;
    auto alloc = [&](size_t bytes) {
        void* p = ws + off;
        off += (bytes + 255) & ~(size_t)255;
        return p;
    };
    int* rowptr  = (int*)alloc((size_t)(N + 1) * 4);
    int* col     = (int*)alloc((size_t)E_ * 4);
    int* gcount  = (int*)alloc(1024 * 4);
    int* bbase   = (int*)alloc(1025 * 4);
    int* gcursor = (int*)alloc(1024 * 4);
    float* partials = (float*)alloc((size_t)G * POOL_PARTS * 64 * 4);
    float* bufA  = (float*)alloc((size_t)N * 64 * 4);
    float* bufB  = (float*)alloc((size_t)N * 64 * 4);
    unsigned* bpack = (unsigned*)bufA;  // alias: bpack dead before proj writes bufA
    (void)ws_size;

    const int nch = (E_ + 2047) / 2048;

    // --- CSR build (bucketed counting sort) ---
    zero1024_kernel<<<1, 1024, 0, stream>>>(gcount);
    count_buckets_kernel<<<nch, 256, 0, stream>>>(ei, gcount, E_);
    scan_buckets_kernel<<<1, 1024, 0, stream>>>(gcount, bbase, gcursor, rowptr, K, E_, N);
    bucketize_kernel<<<nch, 256, 0, stream>>>(ei, gcursor, bpack, E_);
    build_csr_kernel<<<K, 256, 0, stream>>>(bpack, bbase, rowptr, col, N);

    const int ntiles = (N + 63) / 64;
    const int gblocks = (N + 3) / 4;

    // layer 0
    proj128_kernel<<<ntiles, 256, 0, stream>>>(x, bufA, l0w1, N);
    gather64_kernel<<<gblocks, 256, 0, stream>>>(bufA, bufB, rowptr, col, l0b1, N);
    dual_gemv_kernel<true, false><<<ntiles, 256, 0, stream>>>(
        bufB, l0w2, l0b2, l1w1, bufA, nullptr, N);
    // layer 1
    gather64_kernel<<<gblocks, 256, 0, stream>>>(bufA, bufB, rowptr, col, l1b1, N);
    dual_gemv_kernel<true, false><<<ntiles, 256, 0, stream>>>(
        bufB, l1w2, l1b2, l2w1, bufA, nullptr, N);
    // layer 2
    gather64_kernel<<<gblocks, 256, 0, stream>>>(bufA, bufB, rowptr, col, l2b1, N);
    dual_gemv_kernel<false, true><<<ntiles, 256, 0, stream>>>(
        bufB, l2w2, l2b2, nullptr, nullptr, bufB, N);

    // --- pool + head ---
    pool_partial_kernel<<<G * POOL_PARTS, 256, 0, stream>>>(bufB, batch, partials, N);
    pool_head_kernel<<<G, 64, 0, stream>>>(partials, batch, lin1w, lin1b, lin2w, lin2b, out, N);
}

// Round 5
// 360.585 us; speedup vs baseline: 1.8808x; 1.0771x over previous
//
#include <hip/hip_runtime.h>
#include <hip/hip_bf16.h>

// ---------------------------------------------------------------------------
// GIN model, proj-first formulation:
//   per layer: y = h @ w1   (bf16-stored intermediate; aggregate AFTER proj)
//              t = relu(y_self + sum_nbr y + b1)      (fp32)
//              h' = relu(t @ w2 + b2)                  (fused w/ next proj)
// CSR built per call via bucketed counting sort. Pool: 2-stage + head MLP.
// bf16 only on the gathered y buffer (errors wash out in mean-pool).
// ---------------------------------------------------------------------------

__device__ inline unsigned short f2bf(float f) {
    union { __hip_bfloat16 b; unsigned short u; } cv;
    cv.b = __float2bfloat16(f);
    return cv.u;
}
__device__ inline float bf2f(unsigned short u) {
    union { __hip_bfloat16 b; unsigned short u16; } cv;
    cv.u16 = u;
    return __bfloat162float(cv.b);
}

__global__ __launch_bounds__(1024) void zero1024_kernel(int* __restrict__ p) {
    p[threadIdx.x] = 0;
}

__global__ __launch_bounds__(256) void count_buckets_kernel(
    const int* __restrict__ ei, int* __restrict__ gcount, int E_) {
    __shared__ int hist[1024];
    const int tid = threadIdx.x;
    for (int i = tid; i < 1024; i += 256) hist[i] = 0;
    __syncthreads();
    const int base = blockIdx.x * 2048;
#pragma unroll
    for (int i = 0; i < 8; i++) {
        int e = base + i * 256 + tid;
        if (e < E_) atomicAdd(&hist[ei[E_ + e] >> 9], 1);
    }
    __syncthreads();
    for (int i = tid; i < 1024; i += 256)
        if (hist[i]) atomicAdd(&gcount[i], hist[i]);
}

__global__ __launch_bounds__(1024) void scan_buckets_kernel(
    const int* __restrict__ gcount, int* __restrict__ bbase,
    int* __restrict__ gcursor, int* __restrict__ rowptr, int K, int E_, int n) {
    __shared__ int sd[1024];
    const int tid = threadIdx.x;
    int v = (tid < K) ? gcount[tid] : 0;
    sd[tid] = v;
    __syncthreads();
    for (int off = 1; off < 1024; off <<= 1) {
        int x = (tid >= off) ? sd[tid - off] : 0;
        __syncthreads();
        sd[tid] += x;
        __syncthreads();
    }
    if (tid < K) {
        int excl = sd[tid] - v;
        bbase[tid] = excl;
        gcursor[tid] = excl;
    }
    if (tid == 0) {
        bbase[K] = E_;
        rowptr[n] = E_;
    }
}

__global__ __launch_bounds__(256) void bucketize_kernel(
    const int* __restrict__ ei, int* __restrict__ gcursor,
    unsigned* __restrict__ bpack, int E_) {
    __shared__ int hist[1024];
    __shared__ int gbase[1024];
    const int tid = threadIdx.x;
    for (int i = tid; i < 1024; i += 256) hist[i] = 0;
    __syncthreads();
    const int base = blockIdx.x * 2048;
    int bkt[8], rnk[8];
    unsigned pk[8];
#pragma unroll
    for (int i = 0; i < 8; i++) {
        int e = base + i * 256 + tid;
        bkt[i] = -1;
        if (e < E_) {
            int s = ei[e];
            int d = ei[E_ + e];
            bkt[i] = d >> 9;
            pk[i] = (unsigned)s | ((unsigned)(d & 511) << 22);
            rnk[i] = atomicAdd(&hist[bkt[i]], 1);
        }
    }
    __syncthreads();
    for (int i = tid; i < 1024; i += 256)
        if (hist[i]) gbase[i] = atomicAdd(&gcursor[i], hist[i]);
    __syncthreads();
#pragma unroll
    for (int i = 0; i < 8; i++)
        if (bkt[i] >= 0) bpack[gbase[bkt[i]] + rnk[i]] = pk[i];
}

__global__ __launch_bounds__(256) void build_csr_kernel(
    const unsigned* __restrict__ bpack, const int* __restrict__ bbase,
    int* __restrict__ rowptr, int* __restrict__ col, int n) {
    __shared__ int cnt[512];
    __shared__ int sp[256];
    const int tid = threadIdx.x;
    const int b = blockIdx.x;
    const int nstart = b << 9;
    const int estart = bbase[b];
    const int eend = bbase[b + 1];
    cnt[tid] = 0;
    cnt[tid + 256] = 0;
    __syncthreads();
    for (int e = estart + tid; e < eend; e += 256)
        atomicAdd(&cnt[bpack[e] >> 22], 1);
    __syncthreads();
    const int v0 = cnt[tid * 2], v1 = cnt[tid * 2 + 1];
    const int s = v0 + v1;
    sp[tid] = s;
    __syncthreads();
    for (int off = 1; off < 256; off <<= 1) {
        int x = (tid >= off) ? sp[tid - off] : 0;
        __syncthreads();
        sp[tid] += x;
        __syncthreads();
    }
    const int excl = sp[tid] - s;
    cnt[tid * 2] = excl;
    cnt[tid * 2 + 1] = excl + v0;
    const int node0 = nstart + tid * 2;
    if (node0 < n) rowptr[node0] = estart + excl;
    if (node0 + 1 < n) rowptr[node0 + 1] = estart + excl + v0;
    __syncthreads();
    for (int e = estart + tid; e < eend; e += 256) {
        unsigned p = bpack[e];
        int pos = estart + atomicAdd(&cnt[p >> 22], 1);
        col[pos] = (int)(p & 0x3FFFFFu);
    }
}

// ---------------------------------------------------------------------------
// proj128: y[n,64](bf16) = x[n,128] @ w[128,64]
// ---------------------------------------------------------------------------
__global__ __launch_bounds__(256) void proj128_kernel(
    const float* __restrict__ x, unsigned short* __restrict__ y,
    const float* __restrict__ w, int n) {
    constexpr int F = 128, STR = F + 2;
    __shared__ float xs[64 * STR];
    const int tid = threadIdx.x;
    const int tile = blockIdx.x;
    for (int idx = tid; idx < 64 * (F / 2); idx += 256) {
        int r = idx >> 6;
        int c = idx & 63;
        int node = tile * 64 + r;
        float2 v = make_float2(0.f, 0.f);
        if (node < n) v = *reinterpret_cast<const float2*>(x + (size_t)node * F + c * 2);
        *reinterpret_cast<float2*>(&xs[r * STR + c * 2]) = v;
    }
    __syncthreads();
    const int lane = tid & 63;
    const int j0 = __builtin_amdgcn_readfirstlane(tid >> 6) << 4;
    float a[16];
#pragma unroll
    for (int jj = 0; jj < 16; jj++) a[jj] = 0.f;
    for (int k = 0; k < F; k++) {
        const float zk = xs[lane * STR + k];
#pragma unroll
        for (int jj = 0; jj < 16; jj++) a[jj] = fmaf(zk, w[k * 64 + j0 + jj], a[jj]);
    }
    const int node = tile * 64 + lane;
    if (node < n) {
        unsigned pk[8];
#pragma unroll
        for (int jj = 0; jj < 8; jj++)
            pk[jj] = (unsigned)f2bf(a[2 * jj]) | ((unsigned)f2bf(a[2 * jj + 1]) << 16);
        uint4* orow = reinterpret_cast<uint4*>(y + (size_t)node * 64 + j0);
        orow[0] = make_uint4(pk[0], pk[1], pk[2], pk[3]);
        orow[1] = make_uint4(pk[4], pk[5], pk[6], pk[7]);
    }
}

// ---------------------------------------------------------------------------
// gather64: t[node](f32) = relu(y[node] + sum_nbr y[nbr] + b), y in bf16
// One wave per node, lane = feature; col indices wave-uniform (scalar loads).
// ---------------------------------------------------------------------------
__global__ __launch_bounds__(256) void gather64_kernel(
    const unsigned short* __restrict__ y, float* __restrict__ t,
    const int* __restrict__ rowptr, const int* __restrict__ col,
    const float* __restrict__ bias, int n) {
    const int lane = threadIdx.x & 63;
    int node = __builtin_amdgcn_readfirstlane((blockIdx.x * 256 + threadIdx.x) >> 6);
    if (node >= n) return;
    float acc = bf2f(y[(size_t)node * 64 + lane]);
    const int rs = rowptr[node];
    const int re = rowptr[node + 1];
    int p = rs;
    for (; p + 8 <= re; p += 8) {
        int c0 = col[p + 0], c1 = col[p + 1], c2 = col[p + 2], c3 = col[p + 3];
        int c4 = col[p + 4], c5 = col[p + 5], c6 = col[p + 6], c7 = col[p + 7];
        unsigned short v0 = y[(size_t)c0 * 64 + lane];
        unsigned short v1 = y[(size_t)c1 * 64 + lane];
        unsigned short v2 = y[(size_t)c2 * 64 + lane];
        unsigned short v3 = y[(size_t)c3 * 64 + lane];
        unsigned short v4 = y[(size_t)c4 * 64 + lane];
        unsigned short v5 = y[(size_t)c5 * 64 + lane];
        unsigned short v6 = y[(size_t)c6 * 64 + lane];
        unsigned short v7 = y[(size_t)c7 * 64 + lane];
        acc += bf2f(v0); acc += bf2f(v1); acc += bf2f(v2); acc += bf2f(v3);
        acc += bf2f(v4); acc += bf2f(v5); acc += bf2f(v6); acc += bf2f(v7);
    }
    for (; p < re; ++p) acc += bf2f(y[(size_t)col[p] * 64 + lane]);
    t[(size_t)node * 64 + lane] = fmaxf(acc + bias[lane], 0.f);
}

// ---------------------------------------------------------------------------
// dual_gemv: u = relu(t @ w2 + b2); [opt] yout(bf16) = u @ w1n; [opt] hout(f32) = u
// ---------------------------------------------------------------------------
template <bool DO_SECOND, bool WRITE_H>
__global__ __launch_bounds__(256) void dual_gemv_kernel(
    const float* __restrict__ tin,
    const float* __restrict__ w2, const float* __restrict__ b2,
    const float* __restrict__ w1n,
    unsigned short* __restrict__ yout, float* __restrict__ hout, int n) {
    constexpr int STR = 66;
    __shared__ float s1[64 * STR];
    const int tid = threadIdx.x;
    const int tile = blockIdx.x;
    for (int idx = tid; idx < 64 * 32; idx += 256) {
        int r = idx >> 5;
        int c = idx & 31;
        int node = tile * 64 + r;
        float2 v = make_float2(0.f, 0.f);
        if (node < n) v = *reinterpret_cast<const float2*>(tin + (size_t)node * 64 + c * 2);
        *reinterpret_cast<float2*>(&s1[r * STR + c * 2]) = v;
    }
    __syncthreads();
    const int lane = tid & 63;
    const int j0 = __builtin_amdgcn_readfirstlane(tid >> 6) << 4;
    const int node = tile * 64 + lane;
    float a[16];
#pragma unroll
    for (int jj = 0; jj < 16; jj++) a[jj] = b2[j0 + jj];
    for (int k = 0; k < 64; k++) {
        const float tk = s1[lane * STR + k];
#pragma unroll
        for (int jj = 0; jj < 16; jj++) a[jj] = fmaf(tk, w2[k * 64 + j0 + jj], a[jj]);
    }
#pragma unroll
    for (int jj = 0; jj < 16; jj++) a[jj] = fmaxf(a[jj], 0.f);
    if (WRITE_H && node < n) {
        float* orow = hout + (size_t)node * 64 + j0;
#pragma unroll
        for (int jj = 0; jj < 16; jj += 4) {
            *reinterpret_cast<float4*>(orow + jj) =
                make_float4(a[jj], a[jj + 1], a[jj + 2], a[jj + 3]);
        }
    }
    if (DO_SECOND) {
        __syncthreads();
#pragma unroll
        for (int jj = 0; jj < 16; jj++) s1[lane * STR + j0 + jj] = a[jj];
        __syncthreads();
        float a2[16];
#pragma unroll
        for (int jj = 0; jj < 16; jj++) a2[jj] = 0.f;
        for (int k = 0; k < 64; k++) {
            const float uk = s1[lane * STR + k];
#pragma unroll
            for (int jj = 0; jj < 16; jj++) a2[jj] = fmaf(uk, w1n[k * 64 + j0 + jj], a2[jj]);
        }
        if (node < n) {
            unsigned pk[8];
#pragma unroll
            for (int jj = 0; jj < 8; jj++)
                pk[jj] = (unsigned)f2bf(a2[2 * jj]) | ((unsigned)f2bf(a2[2 * jj + 1]) << 16);
            uint4* orow = reinterpret_cast<uint4*>(yout + (size_t)node * 64 + j0);
            orow[0] = make_uint4(pk[0], pk[1], pk[2], pk[3]);
            orow[1] = make_uint4(pk[4], pk[5], pk[6], pk[7]);
        }
    }
}

// ---------------------------------------------------------------------------
// Pool stage 1: G*PARTS blocks; block (g,part) reduces a sub-range of graph g.
// ---------------------------------------------------------------------------
#define POOL_PARTS 16
__global__ __launch_bounds__(256) void pool_partial_kernel(
    const float* __restrict__ h, const int* __restrict__ batch,
    float* __restrict__ partials, int n) {
    const int g = blockIdx.x >> 4;
    const int part = blockIdx.x & 15;
    const int tid = threadIdx.x;
    auto lb = [&](int key) {
        int lo = 0, hi = n;
        while (lo < hi) {
            int mid = (lo + hi) >> 1;
            if (batch[mid] < key) lo = mid + 1;
            else hi = mid;
        }
        return lo;
    };
    const int lo = lb(g), hi = lb(g + 1);
    const int cnt = hi - lo;
    const int s0 = lo + (int)(((long long)cnt * part) / POOL_PARTS);
    const int s1 = lo + (int)(((long long)cnt * (part + 1)) / POOL_PARTS);

    const int f = tid & 63;
    const int q = tid >> 6;
    float s = 0.f;
    for (int i = s0 + q; i < s1; i += 4) s += h[(size_t)i * 64 + f];

    __shared__ float red[256];
    red[tid] = s;
    __syncthreads();
    if (tid < 64) {
        partials[(size_t)blockIdx.x * 64 + tid] =
            red[tid] + red[tid + 64] + red[tid + 128] + red[tid + 192];
    }
}

// ---------------------------------------------------------------------------
// Pool stage 2 + head MLP. One block per graph; reads 16 partials.
// ---------------------------------------------------------------------------
__global__ __launch_bounds__(64) void pool_head_kernel(
    const float* __restrict__ partials, const int* __restrict__ batch,
    const float* __restrict__ l1w, const float* __restrict__ l1b,
    const float* __restrict__ l2w, const float* __restrict__ l2b,
    float* __restrict__ out, int n) {
    const int g = blockIdx.x;
    const int tid = threadIdx.x;
    auto lb = [&](int key) {
        int lo = 0, hi = n;
        while (lo < hi) {
            int mid = (lo + hi) >> 1;
            if (batch[mid] < key) lo = mid + 1;
            else hi = mid;
        }
        return lo;
    };
    const int cnt = lb(g + 1) - lb(g);

    __shared__ float pooled[64];
    __shared__ float r[64];
    float v = 0.f;
#pragma unroll
    for (int p = 0; p < POOL_PARTS; p++)
        v += partials[(size_t)(g * POOL_PARTS + p) * 64 + tid];
    pooled[tid] = v / (float)((cnt > 1) ? cnt : 1);
    __syncthreads();
    float a = l1b[tid];
    for (int k = 0; k < 64; k++) a = fmaf(pooled[k], l1w[k * 64 + tid], a);
    r[tid] = fmaxf(a, 0.f);
    __syncthreads();
    if (tid < 2) {
        float a2 = l2b[tid];
        for (int k = 0; k < 64; k++) a2 = fmaf(r[k], l2w[k * 2 + tid], a2);
        out[g * 2 + tid] = a2;
    }
}

// ---------------------------------------------------------------------------

extern "C" void kernel_launch(void* const* d_in, const int* in_sizes, int n_in,
                              void* d_out, int out_size, void* d_ws, size_t ws_size,
                              hipStream_t stream) {
    const float* x    = (const float*)d_in[0];
    const int* ei     = (const int*)d_in[1];
    const int* batch  = (const int*)d_in[2];
    const float* l0w1 = (const float*)d_in[3];
    const float* l0b1 = (const float*)d_in[4];
    const float* l0w2 = (const float*)d_in[5];
    const float* l0b2 = (const float*)d_in[6];
    const float* l1w1 = (const float*)d_in[7];
    const float* l1b1 = (const float*)d_in[8];
    const float* l1w2 = (const float*)d_in[9];
    const float* l1b2 = (const float*)d_in[10];
    const float* l2w1 = (const float*)d_in[11];
    const float* l2b1 = (const float*)d_in[12];
    const float* l2w2 = (const float*)d_in[13];
    const float* l2b2 = (const float*)d_in[14];
    const float* lin1w = (const float*)d_in[15];
    const float* lin1b = (const float*)d_in[16];
    const float* lin2w = (const float*)d_in[17];
    const float* lin2b = (const float*)d_in[18];
    float* out = (float*)d_out;

    const int N  = in_sizes[2];
    const int E_ = in_sizes[1] / 2;
    const int K  = (N + 511) >> 9;
    const int G  = out_size / 2;

    char* ws = (char*)d_ws;
    size_t off = 0;
    auto alloc = [&](size_t bytes) {
        void* p = ws + off;
        off += (bytes + 255) & ~(size_t)255;
        return p;
    };
    int* rowptr  = (int*)alloc((size_t)(N + 1) * 4);
    int* col     = (int*)alloc((size_t)E_ * 4);
    int* gcount  = (int*)alloc(1024 * 4);
    int* bbase   = (int*)alloc(1025 * 4);
    int* gcursor = (int*)alloc(1024 * 4);
    float* partials = (float*)alloc((size_t)G * POOL_PARTS * 64 * 4);
    unsigned short* ybuf = (unsigned short*)alloc((size_t)N * 64 * 2);
    float* tbuf  = (float*)alloc((size_t)N * 64 * 4);
    float* hbuf  = (float*)alloc((size_t)N * 64 * 4);
    unsigned* bpack = (unsigned*)tbuf;  // alias: bpack dead before gather writes tbuf
    (void)ws_size;

    const int nch = (E_ + 2047) / 2048;

    // --- CSR build (bucketed counting sort) ---
    zero1024_kernel<<<1, 1024, 0, stream>>>(gcount);
    count_buckets_kernel<<<nch, 256, 0, stream>>>(ei, gcount, E_);
    scan_buckets_kernel<<<1, 1024, 0, stream>>>(gcount, bbase, gcursor, rowptr, K, E_, N);
    bucketize_kernel<<<nch, 256, 0, stream>>>(ei, gcursor, bpack, E_);
    build_csr_kernel<<<K, 256, 0, stream>>>(bpack, bbase, rowptr, col, N);

    const int ntiles = (N + 63) / 64;
    const int gblocks = (N + 3) / 4;

    // layer 0
    proj128_kernel<<<ntiles, 256, 0, stream>>>(x, ybuf, l0w1, N);
    gather64_kernel<<<gblocks, 256, 0, stream>>>(ybuf, tbuf, rowptr, col, l0b1, N);
    dual_gemv_kernel<true, false><<<ntiles, 256, 0, stream>>>(
        tbuf, l0w2, l0b2, l1w1, ybuf, nullptr, N);
    // layer 1
    gather64_kernel<<<gblocks, 256, 0, stream>>>(ybuf, tbuf, rowptr, col, l1b1, N);
    dual_gemv_kernel<true, false><<<ntiles, 256, 0, stream>>>(
        tbuf, l1w2, l1b2, l2w1, ybuf, nullptr, N);
    // layer 2
    gather64_kernel<<<gblocks, 256, 0, stream>>>(ybuf, tbuf, rowptr, col, l2b1, N);
    dual_gemv_kernel<false, true><<<ntiles, 256, 0, stream>>>(
        tbuf, l2w2, l2b2, nullptr, nullptr, hbuf, N);

    // --- pool + head ---
    pool_partial_kernel<<<G * POOL_PARTS, 256, 0, stream>>>(hbuf, batch, partials, N);
    pool_head_kernel<<<G, 64, 0, stream>>>(partials, batch, lin1w, lin1b, lin2w, lin2b, out, N);
}

// Round 6
// 338.402 us; speedup vs baseline: 2.0041x; 1.0656x over previous
//
#include <hip/hip_runtime.h>
#include <hip/hip_bf16.h>

// ---------------------------------------------------------------------------
// GIN model, proj-first formulation, fused per-layer kernel:
//   proj:  y0 = x @ w1_0                          (bf16 y)
//   fused: t = relu(y_self + sum_nbr y + b1)      (LDS only, fp32)
//          u = relu(t @ w2 + b2)
//          y' = u @ w1_next  (bf16)   |  h = u (fp32, last layer)
// CSR built per call via bucketed counting sort. Pool: 2-stage + head MLP.
// ---------------------------------------------------------------------------

__device__ inline unsigned short f2bf(float f) {
    union { __hip_bfloat16 b; unsigned short u; } cv;
    cv.b = __float2bfloat16(f);
    return cv.u;
}
__device__ inline float bf2f(unsigned short u) {
    union { __hip_bfloat16 b; unsigned short u16; } cv;
    cv.u16 = u;
    return __bfloat162float(cv.b);
}

__global__ __launch_bounds__(1024) void zero1024_kernel(int* __restrict__ p) {
    p[threadIdx.x] = 0;
}

__global__ __launch_bounds__(256) void count_buckets_kernel(
    const int* __restrict__ ei, int* __restrict__ gcount, int E_) {
    __shared__ int hist[1024];
    const int tid = threadIdx.x;
    for (int i = tid; i < 1024; i += 256) hist[i] = 0;
    __syncthreads();
    const int base = blockIdx.x * 2048;
#pragma unroll
    for (int i = 0; i < 8; i++) {
        int e = base + i * 256 + tid;
        if (e < E_) atomicAdd(&hist[ei[E_ + e] >> 9], 1);
    }
    __syncthreads();
    for (int i = tid; i < 1024; i += 256)
        if (hist[i]) atomicAdd(&gcount[i], hist[i]);
}

__global__ __launch_bounds__(1024) void scan_buckets_kernel(
    const int* __restrict__ gcount, int* __restrict__ bbase,
    int* __restrict__ gcursor, int* __restrict__ rowptr, int K, int E_, int n) {
    __shared__ int sd[1024];
    const int tid = threadIdx.x;
    int v = (tid < K) ? gcount[tid] : 0;
    sd[tid] = v;
    __syncthreads();
    for (int off = 1; off < 1024; off <<= 1) {
        int x = (tid >= off) ? sd[tid - off] : 0;
        __syncthreads();
        sd[tid] += x;
        __syncthreads();
    }
    if (tid < K) {
        int excl = sd[tid] - v;
        bbase[tid] = excl;
        gcursor[tid] = excl;
    }
    if (tid == 0) {
        bbase[K] = E_;
        rowptr[n] = E_;
    }
}

__global__ __launch_bounds__(256) void bucketize_kernel(
    const int* __restrict__ ei, int* __restrict__ gcursor,
    unsigned* __restrict__ bpack, int E_) {
    __shared__ int hist[1024];
    __shared__ int gbase[1024];
    const int tid = threadIdx.x;
    for (int i = tid; i < 1024; i += 256) hist[i] = 0;
    __syncthreads();
    const int base = blockIdx.x * 2048;
    int bkt[8], rnk[8];
    unsigned pk[8];
#pragma unroll
    for (int i = 0; i < 8; i++) {
        int e = base + i * 256 + tid;
        bkt[i] = -1;
        if (e < E_) {
            int s = ei[e];
            int d = ei[E_ + e];
            bkt[i] = d >> 9;
            pk[i] = (unsigned)s | ((unsigned)(d & 511) << 22);
            rnk[i] = atomicAdd(&hist[bkt[i]], 1);
        }
    }
    __syncthreads();
    for (int i = tid; i < 1024; i += 256)
        if (hist[i]) gbase[i] = atomicAdd(&gcursor[i], hist[i]);
    __syncthreads();
#pragma unroll
    for (int i = 0; i < 8; i++)
        if (bkt[i] >= 0) bpack[gbase[bkt[i]] + rnk[i]] = pk[i];
}

__global__ __launch_bounds__(256) void build_csr_kernel(
    const unsigned* __restrict__ bpack, const int* __restrict__ bbase,
    int* __restrict__ rowptr, int* __restrict__ col, int n) {
    __shared__ int cnt[512];
    __shared__ int sp[256];
    const int tid = threadIdx.x;
    const int b = blockIdx.x;
    const int nstart = b << 9;
    const int estart = bbase[b];
    const int eend = bbase[b + 1];
    cnt[tid] = 0;
    cnt[tid + 256] = 0;
    __syncthreads();
    for (int e = estart + tid; e < eend; e += 256)
        atomicAdd(&cnt[bpack[e] >> 22], 1);
    __syncthreads();
    const int v0 = cnt[tid * 2], v1 = cnt[tid * 2 + 1];
    const int s = v0 + v1;
    sp[tid] = s;
    __syncthreads();
    for (int off = 1; off < 256; off <<= 1) {
        int x = (tid >= off) ? sp[tid - off] : 0;
        __syncthreads();
        sp[tid] += x;
        __syncthreads();
    }
    const int excl = sp[tid] - s;
    cnt[tid * 2] = excl;
    cnt[tid * 2 + 1] = excl + v0;
    const int node0 = nstart + tid * 2;
    if (node0 < n) rowptr[node0] = estart + excl;
    if (node0 + 1 < n) rowptr[node0 + 1] = estart + excl + v0;
    __syncthreads();
    for (int e = estart + tid; e < eend; e += 256) {
        unsigned p = bpack[e];
        int pos = estart + atomicAdd(&cnt[p >> 22], 1);
        col[pos] = (int)(p & 0x3FFFFFu);
    }
}

// ---------------------------------------------------------------------------
// proj128: y[n,64](bf16) = x[n,128] @ w[128,64]
// ---------------------------------------------------------------------------
__global__ __launch_bounds__(256) void proj128_kernel(
    const float* __restrict__ x, unsigned short* __restrict__ y,
    const float* __restrict__ w, int n) {
    constexpr int F = 128, STR = F + 2;
    __shared__ float xs[64 * STR];
    const int tid = threadIdx.x;
    const int tile = blockIdx.x;
    for (int idx = tid; idx < 64 * (F / 2); idx += 256) {
        int r = idx >> 6;
        int c = idx & 63;
        int node = tile * 64 + r;
        float2 v = make_float2(0.f, 0.f);
        if (node < n) v = *reinterpret_cast<const float2*>(x + (size_t)node * F + c * 2);
        *reinterpret_cast<float2*>(&xs[r * STR + c * 2]) = v;
    }
    __syncthreads();
    const int lane = tid & 63;
    const int j0 = __builtin_amdgcn_readfirstlane(tid >> 6) << 4;
    float a[16];
#pragma unroll
    for (int jj = 0; jj < 16; jj++) a[jj] = 0.f;
    for (int k = 0; k < F; k += 8) {
        float2 t0 = *reinterpret_cast<const float2*>(&xs[lane * STR + k]);
        float2 t1 = *reinterpret_cast<const float2*>(&xs[lane * STR + k + 2]);
        float2 t2 = *reinterpret_cast<const float2*>(&xs[lane * STR + k + 4]);
        float2 t3 = *reinterpret_cast<const float2*>(&xs[lane * STR + k + 6]);
        const float tv[8] = {t0.x, t0.y, t1.x, t1.y, t2.x, t2.y, t3.x, t3.y};
#pragma unroll
        for (int kk = 0; kk < 8; kk++)
#pragma unroll
            for (int jj = 0; jj < 16; jj++)
                a[jj] = fmaf(tv[kk], w[(k + kk) * 64 + j0 + jj], a[jj]);
    }
    const int node = tile * 64 + lane;
    if (node < n) {
        unsigned pk[8];
#pragma unroll
        for (int jj = 0; jj < 8; jj++)
            pk[jj] = (unsigned)f2bf(a[2 * jj]) | ((unsigned)f2bf(a[2 * jj + 1]) << 16);
        uint4* orow = reinterpret_cast<uint4*>(y + (size_t)node * 64 + j0);
        orow[0] = make_uint4(pk[0], pk[1], pk[2], pk[3]);
        orow[1] = make_uint4(pk[4], pk[5], pk[6], pk[7]);
    }
}

// ---------------------------------------------------------------------------
// fused_layer: per 64-node tile
//   A: t = relu(y_self + sum_nbr y + b1) -> LDS (wave gathers 16 nodes)
//   B: u = relu(t @ w2 + b2)
//   C/D (mid): y' = u @ w1n  (bf16)   |  (last): h = u (fp32)
// ---------------------------------------------------------------------------
template <bool LAST>
__global__ __launch_bounds__(256) void fused_layer_kernel(
    const unsigned short* __restrict__ yin,
    const int* __restrict__ rowptr, const int* __restrict__ col,
    const float* __restrict__ b1,
    const float* __restrict__ w2, const float* __restrict__ b2,
    const float* __restrict__ w1n,
    unsigned short* __restrict__ yout, float* __restrict__ hout, int n) {
    constexpr int STR = 66;
    __shared__ float tl[64 * STR];
    const int tid = threadIdx.x;
    const int tile = blockIdx.x;
    const int lane = tid & 63;
    const int wv = __builtin_amdgcn_readfirstlane(tid >> 6);
    const float bias1 = b1[lane];

    // ---- Phase A: gather (wave handles 16 consecutive nodes) ----
    for (int i = 0; i < 16; ++i) {
        const int node = tile * 64 + wv * 16 + i;
        if (node >= n) break;  // nodes ascending; uniform per wave
        float acc = bf2f(yin[(size_t)node * 64 + lane]);
        const int rs = rowptr[node];
        const int re = rowptr[node + 1];
        int p = rs;
        for (; p + 8 <= re; p += 8) {
            int c0 = col[p + 0], c1 = col[p + 1], c2 = col[p + 2], c3 = col[p + 3];
            int c4 = col[p + 4], c5 = col[p + 5], c6 = col[p + 6], c7 = col[p + 7];
            unsigned short v0 = yin[(size_t)c0 * 64 + lane];
            unsigned short v1 = yin[(size_t)c1 * 64 + lane];
            unsigned short v2 = yin[(size_t)c2 * 64 + lane];
            unsigned short v3 = yin[(size_t)c3 * 64 + lane];
            unsigned short v4 = yin[(size_t)c4 * 64 + lane];
            unsigned short v5 = yin[(size_t)c5 * 64 + lane];
            unsigned short v6 = yin[(size_t)c6 * 64 + lane];
            unsigned short v7 = yin[(size_t)c7 * 64 + lane];
            acc += bf2f(v0); acc += bf2f(v1); acc += bf2f(v2); acc += bf2f(v3);
            acc += bf2f(v4); acc += bf2f(v5); acc += bf2f(v6); acc += bf2f(v7);
        }
        for (; p < re; ++p) acc += bf2f(yin[(size_t)col[p] * 64 + lane]);
        tl[(wv * 16 + i) * STR + lane] = fmaxf(acc + bias1, 0.f);
    }
    __syncthreads();

    // ---- Phase B: u = relu(t @ w2 + b2) ----
    const int j0 = wv << 4;
    const int node = tile * 64 + lane;
    float a[16];
#pragma unroll
    for (int jj = 0; jj < 16; jj++) a[jj] = b2[j0 + jj];
    for (int k = 0; k < 64; k += 8) {
        float2 t0 = *reinterpret_cast<const float2*>(&tl[lane * STR + k]);
        float2 t1 = *reinterpret_cast<const float2*>(&tl[lane * STR + k + 2]);
        float2 t2 = *reinterpret_cast<const float2*>(&tl[lane * STR + k + 4]);
        float2 t3 = *reinterpret_cast<const float2*>(&tl[lane * STR + k + 6]);
        const float tv[8] = {t0.x, t0.y, t1.x, t1.y, t2.x, t2.y, t3.x, t3.y};
#pragma unroll
        for (int kk = 0; kk < 8; kk++)
#pragma unroll
            for (int jj = 0; jj < 16; jj++)
                a[jj] = fmaf(tv[kk], w2[(k + kk) * 64 + j0 + jj], a[jj]);
    }
#pragma unroll
    for (int jj = 0; jj < 16; jj++) a[jj] = fmaxf(a[jj], 0.f);

    if (LAST) {
        if (node < n) {
            float* orow = hout + (size_t)node * 64 + j0;
#pragma unroll
            for (int jj = 0; jj < 16; jj += 4) {
                *reinterpret_cast<float4*>(orow + jj) =
                    make_float4(a[jj], a[jj + 1], a[jj + 2], a[jj + 3]);
            }
        }
    } else {
        // ---- Phase C: overlay u into LDS ----
        __syncthreads();
#pragma unroll
        for (int jj = 0; jj < 16; jj++) tl[lane * STR + j0 + jj] = a[jj];
        __syncthreads();
        // ---- Phase D: y' = u @ w1n ----
        float a2[16];
#pragma unroll
        for (int jj = 0; jj < 16; jj++) a2[jj] = 0.f;
        for (int k = 0; k < 64; k += 8) {
            float2 t0 = *reinterpret_cast<const float2*>(&tl[lane * STR + k]);
            float2 t1 = *reinterpret_cast<const float2*>(&tl[lane * STR + k + 2]);
            float2 t2 = *reinterpret_cast<const float2*>(&tl[lane * STR + k + 4]);
            float2 t3 = *reinterpret_cast<const float2*>(&tl[lane * STR + k + 6]);
            const float tv[8] = {t0.x, t0.y, t1.x, t1.y, t2.x, t2.y, t3.x, t3.y};
#pragma unroll
            for (int kk = 0; kk < 8; kk++)
#pragma unroll
                for (int jj = 0; jj < 16; jj++)
                    a2[jj] = fmaf(tv[kk], w1n[(k + kk) * 64 + j0 + jj], a2[jj]);
        }
        if (node < n) {
            unsigned pk[8];
#pragma unroll
            for (int jj = 0; jj < 8; jj++)
                pk[jj] = (unsigned)f2bf(a2[2 * jj]) | ((unsigned)f2bf(a2[2 * jj + 1]) << 16);
            uint4* orow = reinterpret_cast<uint4*>(yout + (size_t)node * 64 + j0);
            orow[0] = make_uint4(pk[0], pk[1], pk[2], pk[3]);
            orow[1] = make_uint4(pk[4], pk[5], pk[6], pk[7]);
        }
    }
}

// ---------------------------------------------------------------------------
// Pool stage 1: G*PARTS blocks; block (g,part) reduces a sub-range of graph g.
// ---------------------------------------------------------------------------
#define POOL_PARTS 16
__global__ __launch_bounds__(256) void pool_partial_kernel(
    const float* __restrict__ h, const int* __restrict__ batch,
    float* __restrict__ partials, int n) {
    const int g = blockIdx.x >> 4;
    const int part = blockIdx.x & 15;
    const int tid = threadIdx.x;
    auto lb = [&](int key) {
        int lo = 0, hi = n;
        while (lo < hi) {
            int mid = (lo + hi) >> 1;
            if (batch[mid] < key) lo = mid + 1;
            else hi = mid;
        }
        return lo;
    };
    const int lo = lb(g), hi = lb(g + 1);
    const int cnt = hi - lo;
    const int s0 = lo + (int)(((long long)cnt * part) / POOL_PARTS);
    const int s1 = lo + (int)(((long long)cnt * (part + 1)) / POOL_PARTS);

    const int f = tid & 63;
    const int q = tid >> 6;
    float s = 0.f;
    for (int i = s0 + q; i < s1; i += 4) s += h[(size_t)i * 64 + f];

    __shared__ float red[256];
    red[tid] = s;
    __syncthreads();
    if (tid < 64) {
        partials[(size_t)blockIdx.x * 64 + tid] =
            red[tid] + red[tid + 64] + red[tid + 128] + red[tid + 192];
    }
}

// ---------------------------------------------------------------------------
// Pool stage 2 + head MLP. One block per graph; reads 16 partials.
// ---------------------------------------------------------------------------
__global__ __launch_bounds__(64) void pool_head_kernel(
    const float* __restrict__ partials, const int* __restrict__ batch,
    const float* __restrict__ l1w, const float* __restrict__ l1b,
    const float* __restrict__ l2w, const float* __restrict__ l2b,
    float* __restrict__ out, int n) {
    const int g = blockIdx.x;
    const int tid = threadIdx.x;
    auto lb = [&](int key) {
        int lo = 0, hi = n;
        while (lo < hi) {
            int mid = (lo + hi) >> 1;
            if (batch[mid] < key) lo = mid + 1;
            else hi = mid;
        }
        return lo;
    };
    const int cnt = lb(g + 1) - lb(g);

    __shared__ float pooled[64];
    __shared__ float r[64];
    float v = 0.f;
#pragma unroll
    for (int p = 0; p < POOL_PARTS; p++)
        v += partials[(size_t)(g * POOL_PARTS + p) * 64 + tid];
    pooled[tid] = v / (float)((cnt > 1) ? cnt : 1);
    __syncthreads();
    float a = l1b[tid];
    for (int k = 0; k < 64; k++) a = fmaf(pooled[k], l1w[k * 64 + tid], a);
    r[tid] = fmaxf(a, 0.f);
    __syncthreads();
    if (tid < 2) {
        float a2 = l2b[tid];
        for (int k = 0; k < 64; k++) a2 = fmaf(r[k], l2w[k * 2 + tid], a2);
        out[g * 2 + tid] = a2;
    }
}

// ---------------------------------------------------------------------------

extern "C" void kernel_launch(void* const* d_in, const int* in_sizes, int n_in,
                              void* d_out, int out_size, void* d_ws, size_t ws_size,
                              hipStream_t stream) {
    const float* x    = (const float*)d_in[0];
    const int* ei     = (const int*)d_in[1];
    const int* batch  = (const int*)d_in[2];
    const float* l0w1 = (const float*)d_in[3];
    const float* l0b1 = (const float*)d_in[4];
    const float* l0w2 = (const float*)d_in[5];
    const float* l0b2 = (const float*)d_in[6];
    const float* l1w1 = (const float*)d_in[7];
    const float* l1b1 = (const float*)d_in[8];
    const float* l1w2 = (const float*)d_in[9];
    const float* l1b2 = (const float*)d_in[10];
    const float* l2w1 = (const float*)d_in[11];
    const float* l2b1 = (const float*)d_in[12];
    const float* l2w2 = (const float*)d_in[13];
    const float* l2b2 = (const float*)d_in[14];
    const float* lin1w = (const float*)d_in[15];
    const float* lin1b = (const float*)d_in[16];
    const float* lin2w = (const float*)d_in[17];
    const float* lin2b = (const float*)d_in[18];
    float* out = (float*)d_out;

    const int N  = in_sizes[2];
    const int E_ = in_sizes[1] / 2;
    const int K  = (N + 511) >> 9;
    const int G  = out_size / 2;

    char* ws = (char*)d_ws;
    size_t off = 0;
    auto alloc = [&](size_t bytes) {
        void* p = ws + off;
        off += (bytes + 255) & ~(size_t)255;
        return p;
    };
    int* rowptr  = (int*)alloc((size_t)(N + 1) * 4);
    int* col     = (int*)alloc((size_t)E_ * 4);
    int* gcount  = (int*)alloc(1024 * 4);
    int* bbase   = (int*)alloc(1025 * 4);
    int* gcursor = (int*)alloc(1024 * 4);
    float* partials = (float*)alloc((size_t)G * POOL_PARTS * 64 * 4);
    unsigned short* yA = (unsigned short*)alloc((size_t)N * 64 * 2);
    unsigned short* yB = (unsigned short*)alloc((size_t)N * 64 * 2);
    float* hbuf  = (float*)alloc((size_t)N * 64 * 4);
    unsigned* bpack = (unsigned*)hbuf;  // alias: bpack dead before fused2 writes hbuf
    (void)ws_size;

    const int nch = (E_ + 2047) / 2048;

    // --- CSR build (bucketed counting sort) ---
    zero1024_kernel<<<1, 1024, 0, stream>>>(gcount);
    count_buckets_kernel<<<nch, 256, 0, stream>>>(ei, gcount, E_);
    scan_buckets_kernel<<<1, 1024, 0, stream>>>(gcount, bbase, gcursor, rowptr, K, E_, N);
    bucketize_kernel<<<nch, 256, 0, stream>>>(ei, gcursor, bpack, E_);
    build_csr_kernel<<<K, 256, 0, stream>>>(bpack, bbase, rowptr, col, N);

    const int ntiles = (N + 63) / 64;

    // layer 0 proj, then 3 fused layers
    proj128_kernel<<<ntiles, 256, 0, stream>>>(x, yA, l0w1, N);
    fused_layer_kernel<false><<<ntiles, 256, 0, stream>>>(
        yA, rowptr, col, l0b1, l0w2, l0b2, l1w1, yB, nullptr, N);
    fused_layer_kernel<false><<<ntiles, 256, 0, stream>>>(
        yB, rowptr, col, l1b1, l1w2, l1b2, l2w1, yA, nullptr, N);
    fused_layer_kernel<true><<<ntiles, 256, 0, stream>>>(
        yA, rowptr, col, l2b1, l2w2, l2b2, nullptr, nullptr, hbuf, N);

    // --- pool + head ---
    pool_partial_kernel<<<G * POOL_PARTS, 256, 0, stream>>>(hbuf, batch, partials, N);
    pool_head_kernel<<<G, 64, 0, stream>>>(partials, batch, lin1w, lin1b, lin2w, lin2b, out, N);
}

// Round 7
// 310.029 us; speedup vs baseline: 2.1875x; 1.0915x over previous
//
#include <hip/hip_runtime.h>
#include <hip/hip_bf16.h>

// ---------------------------------------------------------------------------
// GIN model, proj-first formulation, fused per-layer kernel:
//   proj:  y0 = x @ w1_0                          (bf16 y, bf16 x-tile in LDS)
//   fused: t = relu(y_self + sum_nbr y + b1)      (LDS only, fp32)
//          u = relu(t @ w2 + b2)
//          y' = u @ w1_next  (bf16)   |  h = u (fp32, last layer)
// Gather: pair-of-nodes x half-wave dword loads (32 nbrs per latency batch).
// CSR built per call via bucketed counting sort. Pool: 2-stage + head MLP.
// ---------------------------------------------------------------------------

__device__ inline unsigned short f2bf(float f) {
    union { __hip_bfloat16 b; unsigned short u; } cv;
    cv.b = __float2bfloat16(f);
    return cv.u;
}
__device__ inline float bflo(unsigned int v) {
    union { unsigned int u; float f; } c; c.u = v << 16; return c.f;
}
__device__ inline float bfhi(unsigned int v) {
    union { unsigned int u; float f; } c; c.u = v & 0xffff0000u; return c.f;
}

__global__ __launch_bounds__(1024) void zero1024_kernel(int* __restrict__ p) {
    p[threadIdx.x] = 0;
}

__global__ __launch_bounds__(256) void count_buckets_kernel(
    const int* __restrict__ ei, int* __restrict__ gcount, int E_) {
    __shared__ int hist[1024];
    const int tid = threadIdx.x;
    for (int i = tid; i < 1024; i += 256) hist[i] = 0;
    __syncthreads();
    const int base = blockIdx.x * 2048;
#pragma unroll
    for (int i = 0; i < 8; i++) {
        int e = base + i * 256 + tid;
        if (e < E_) atomicAdd(&hist[ei[E_ + e] >> 9], 1);
    }
    __syncthreads();
    for (int i = tid; i < 1024; i += 256)
        if (hist[i]) atomicAdd(&gcount[i], hist[i]);
}

__global__ __launch_bounds__(1024) void scan_buckets_kernel(
    const int* __restrict__ gcount, int* __restrict__ bbase,
    int* __restrict__ gcursor, int* __restrict__ rowptr, int K, int E_, int n) {
    __shared__ int sd[1024];
    const int tid = threadIdx.x;
    int v = (tid < K) ? gcount[tid] : 0;
    sd[tid] = v;
    __syncthreads();
    for (int off = 1; off < 1024; off <<= 1) {
        int x = (tid >= off) ? sd[tid - off] : 0;
        __syncthreads();
        sd[tid] += x;
        __syncthreads();
    }
    if (tid < K) {
        int excl = sd[tid] - v;
        bbase[tid] = excl;
        gcursor[tid] = excl;
    }
    if (tid == 0) {
        bbase[K] = E_;
        rowptr[n] = E_;
    }
}

__global__ __launch_bounds__(256) void bucketize_kernel(
    const int* __restrict__ ei, int* __restrict__ gcursor,
    unsigned* __restrict__ bpack, int E_) {
    __shared__ int hist[1024];
    __shared__ int gbase[1024];
    const int tid = threadIdx.x;
    for (int i = tid; i < 1024; i += 256) hist[i] = 0;
    __syncthreads();
    const int base = blockIdx.x * 2048;
    int bkt[8], rnk[8];
    unsigned pk[8];
#pragma unroll
    for (int i = 0; i < 8; i++) {
        int e = base + i * 256 + tid;
        bkt[i] = -1;
        if (e < E_) {
            int s = ei[e];
            int d = ei[E_ + e];
            bkt[i] = d >> 9;
            pk[i] = (unsigned)s | ((unsigned)(d & 511) << 22);
            rnk[i] = atomicAdd(&hist[bkt[i]], 1);
        }
    }
    __syncthreads();
    for (int i = tid; i < 1024; i += 256)
        if (hist[i]) gbase[i] = atomicAdd(&gcursor[i], hist[i]);
    __syncthreads();
#pragma unroll
    for (int i = 0; i < 8; i++)
        if (bkt[i] >= 0) bpack[gbase[bkt[i]] + rnk[i]] = pk[i];
}

__global__ __launch_bounds__(256) void build_csr_kernel(
    const unsigned* __restrict__ bpack, const int* __restrict__ bbase,
    int* __restrict__ rowptr, int* __restrict__ col, int n) {
    __shared__ int cnt[512];
    __shared__ int sp[256];
    const int tid = threadIdx.x;
    const int b = blockIdx.x;
    const int nstart = b << 9;
    const int estart = bbase[b];
    const int eend = bbase[b + 1];
    cnt[tid] = 0;
    cnt[tid + 256] = 0;
    __syncthreads();
    for (int e = estart + tid; e < eend; e += 256)
        atomicAdd(&cnt[bpack[e] >> 22], 1);
    __syncthreads();
    const int v0 = cnt[tid * 2], v1 = cnt[tid * 2 + 1];
    const int s = v0 + v1;
    sp[tid] = s;
    __syncthreads();
    for (int off = 1; off < 256; off <<= 1) {
        int x = (tid >= off) ? sp[tid - off] : 0;
        __syncthreads();
        sp[tid] += x;
        __syncthreads();
    }
    const int excl = sp[tid] - s;
    cnt[tid * 2] = excl;
    cnt[tid * 2 + 1] = excl + v0;
    const int node0 = nstart + tid * 2;
    if (node0 < n) rowptr[node0] = estart + excl;
    if (node0 + 1 < n) rowptr[node0 + 1] = estart + excl + v0;
    __syncthreads();
    for (int e = estart + tid; e < eend; e += 256) {
        unsigned p = bpack[e];
        int pos = estart + atomicAdd(&cnt[p >> 22], 1);
        col[pos] = (int)(p & 0x3FFFFFu);
    }
}

// ---------------------------------------------------------------------------
// proj128: y[n,64](bf16) = x[n,128] @ w[128,64]; x staged bf16x2 in LDS.
// ---------------------------------------------------------------------------
__global__ __launch_bounds__(256) void proj128_kernel(
    const float* __restrict__ x, unsigned short* __restrict__ y,
    const float* __restrict__ w, int n) {
    constexpr int STR = 66;              // u32 stride (2-way bank alias: free)
    __shared__ unsigned int xs[64 * STR];
    const int tid = threadIdx.x;
    const int tile = blockIdx.x;
    // stage 64 rows x 128 floats -> bf16x2 (coalesced float2 reads)
    for (int idx = tid; idx < 64 * 64; idx += 256) {
        int r = idx >> 6;
        int c = idx & 63;
        int node = tile * 64 + r;
        float2 v = make_float2(0.f, 0.f);
        if (node < n) v = *reinterpret_cast<const float2*>(x + (size_t)node * 128 + c * 2);
        xs[r * STR + c] = (unsigned)f2bf(v.x) | ((unsigned)f2bf(v.y) << 16);
    }
    __syncthreads();
    const int lane = tid & 63;
    const int j0 = __builtin_amdgcn_readfirstlane(tid >> 6) << 4;
    float a[16];
#pragma unroll
    for (int jj = 0; jj < 16; jj++) a[jj] = 0.f;
    for (int k = 0; k < 128; k += 8) {
        unsigned p0 = xs[lane * STR + k / 2 + 0];
        unsigned p1 = xs[lane * STR + k / 2 + 1];
        unsigned p2 = xs[lane * STR + k / 2 + 2];
        unsigned p3 = xs[lane * STR + k / 2 + 3];
        const float tv[8] = {bflo(p0), bfhi(p0), bflo(p1), bfhi(p1),
                             bflo(p2), bfhi(p2), bflo(p3), bfhi(p3)};
#pragma unroll
        for (int kk = 0; kk < 8; kk++)
#pragma unroll
            for (int jj = 0; jj < 16; jj++)
                a[jj] = fmaf(tv[kk], w[(k + kk) * 64 + j0 + jj], a[jj]);
    }
    const int node = tile * 64 + lane;
    if (node < n) {
        unsigned pk[8];
#pragma unroll
        for (int jj = 0; jj < 8; jj++)
            pk[jj] = (unsigned)f2bf(a[2 * jj]) | ((unsigned)f2bf(a[2 * jj + 1]) << 16);
        uint4* orow = reinterpret_cast<uint4*>(y + (size_t)node * 64 + j0);
        orow[0] = make_uint4(pk[0], pk[1], pk[2], pk[3]);
        orow[1] = make_uint4(pk[4], pk[5], pk[6], pk[7]);
    }
}

// ---------------------------------------------------------------------------
// fused_layer: per 64-node tile
//   A: t = relu(y_self + sum_nbr y + b1) -> LDS
//      pair-of-nodes x half-wave: lane covers features {2*sub, 2*sub+1};
//      half 0 takes even neighbor slots, half 1 odd; 32 nbrs per batch.
//   B: u = relu(t @ w2 + b2)
//   C/D (mid): y' = u @ w1n (bf16)   |  (last): h = u (fp32)
// ---------------------------------------------------------------------------
template <bool LAST>
__global__ __launch_bounds__(256) void fused_layer_kernel(
    const unsigned short* __restrict__ yin,
    const int* __restrict__ rowptr, const int* __restrict__ col,
    const float* __restrict__ b1,
    const float* __restrict__ w2, const float* __restrict__ b2,
    const float* __restrict__ w1n,
    unsigned short* __restrict__ yout, float* __restrict__ hout, int n) {
    constexpr int STR = 66;
    __shared__ float tl[64 * STR];
    const int tid = threadIdx.x;
    const int tile = blockIdx.x;
    const int lane = tid & 63;
    const int wv = __builtin_amdgcn_readfirstlane(tid >> 6);
    const int sub = lane & 31;
    const int h = lane >> 5;
    const unsigned int* y32 = reinterpret_cast<const unsigned int*>(yin);
    const float2 b1v = *reinterpret_cast<const float2*>(b1 + 2 * sub);

    // ---- Phase A: gather, 8 node-pairs per wave ----
    for (int j = 0; j < 8; ++j) {
        const int iA = wv * 16 + 2 * j;
        const int iB = iA + 1;
        const int nA = tile * 64 + iA;
        const int nB = nA + 1;
        int rsA = 0, reA = 0, rsB = 0, reB = 0;
        if (nA < n) { rsA = rowptr[nA]; reA = rowptr[nA + 1]; }
        if (nB < n) { rsB = rowptr[nB]; reB = rowptr[nB + 1]; }
        const int degA = reA - rsA;
        const int degB = reB - rsB;
        float2 accA = make_float2(0.f, 0.f);
        float2 accB = make_float2(0.f, 0.f);
        // self rows: one load, half0 -> A, half1 -> B
        {
            const int sn = h ? nB : nA;
            unsigned int sv = 0;
            if (sn < n) sv = y32[(size_t)sn * 32 + sub];
            const float slo = bflo(sv), shi = bfhi(sv);
            accA.x += h ? 0.f : slo;  accA.y += h ? 0.f : shi;
            accB.x += h ? slo : 0.f;  accB.y += h ? shi : 0.f;
        }
        const int mdeg = degA > degB ? degA : degB;
        for (int base = 0; base < mdeg; base += 16) {
            int ca[8], cb[8];
#pragma unroll
            for (int k = 0; k < 8; ++k) {
                const int q = base + 2 * k + h;
                ca[k] = (q < degA) ? col[rsA + q] : -1;
                cb[k] = (q < degB) ? col[rsB + q] : -1;
            }
            unsigned int va[8], vb[8];
#pragma unroll
            for (int k = 0; k < 8; ++k) {
                va[k] = (ca[k] >= 0) ? y32[(size_t)ca[k] * 32 + sub] : 0u;
                vb[k] = (cb[k] >= 0) ? y32[(size_t)cb[k] * 32 + sub] : 0u;
            }
#pragma unroll
            for (int k = 0; k < 8; ++k) {
                accA.x += bflo(va[k]); accA.y += bfhi(va[k]);
                accB.x += bflo(vb[k]); accB.y += bfhi(vb[k]);
            }
        }
        // combine halves (deterministic), apply bias+relu, write to LDS
        accA.x += __shfl_xor(accA.x, 32);
        accA.y += __shfl_xor(accA.y, 32);
        accB.x += __shfl_xor(accB.x, 32);
        accB.y += __shfl_xor(accB.y, 32);
        const int wi = h ? iB : iA;
        float2 wv2 = h ? accB : accA;
        wv2.x = fmaxf(wv2.x + b1v.x, 0.f);
        wv2.y = fmaxf(wv2.y + b1v.y, 0.f);
        if (tile * 64 + wi < n)
            *reinterpret_cast<float2*>(&tl[wi * STR + 2 * sub]) = wv2;
    }
    __syncthreads();

    // ---- Phase B: u = relu(t @ w2 + b2) ----
    const int j0 = wv << 4;
    const int node = tile * 64 + lane;
    float a[16];
#pragma unroll
    for (int jj = 0; jj < 16; jj++) a[jj] = b2[j0 + jj];
    for (int k = 0; k < 64; k += 8) {
        float2 t0 = *reinterpret_cast<const float2*>(&tl[lane * STR + k]);
        float2 t1 = *reinterpret_cast<const float2*>(&tl[lane * STR + k + 2]);
        float2 t2 = *reinterpret_cast<const float2*>(&tl[lane * STR + k + 4]);
        float2 t3 = *reinterpret_cast<const float2*>(&tl[lane * STR + k + 6]);
        const float tv[8] = {t0.x, t0.y, t1.x, t1.y, t2.x, t2.y, t3.x, t3.y};
#pragma unroll
        for (int kk = 0; kk < 8; kk++)
#pragma unroll
            for (int jj = 0; jj < 16; jj++)
                a[jj] = fmaf(tv[kk], w2[(k + kk) * 64 + j0 + jj], a[jj]);
    }
#pragma unroll
    for (int jj = 0; jj < 16; jj++) a[jj] = fmaxf(a[jj], 0.f);

    if (LAST) {
        if (node < n) {
            float* orow = hout + (size_t)node * 64 + j0;
#pragma unroll
            for (int jj = 0; jj < 16; jj += 4) {
                *reinterpret_cast<float4*>(orow + jj) =
                    make_float4(a[jj], a[jj + 1], a[jj + 2], a[jj + 3]);
            }
        }
    } else {
        __syncthreads();
#pragma unroll
        for (int jj = 0; jj < 16; jj++) tl[lane * STR + j0 + jj] = a[jj];
        __syncthreads();
        float a2[16];
#pragma unroll
        for (int jj = 0; jj < 16; jj++) a2[jj] = 0.f;
        for (int k = 0; k < 64; k += 8) {
            float2 t0 = *reinterpret_cast<const float2*>(&tl[lane * STR + k]);
            float2 t1 = *reinterpret_cast<const float2*>(&tl[lane * STR + k + 2]);
            float2 t2 = *reinterpret_cast<const float2*>(&tl[lane * STR + k + 4]);
            float2 t3 = *reinterpret_cast<const float2*>(&tl[lane * STR + k + 6]);
            const float tv[8] = {t0.x, t0.y, t1.x, t1.y, t2.x, t2.y, t3.x, t3.y};
#pragma unroll
            for (int kk = 0; kk < 8; kk++)
#pragma unroll
                for (int jj = 0; jj < 16; jj++)
                    a2[jj] = fmaf(tv[kk], w1n[(k + kk) * 64 + j0 + jj], a2[jj]);
        }
        if (node < n) {
            unsigned pk[8];
#pragma unroll
            for (int jj = 0; jj < 8; jj++)
                pk[jj] = (unsigned)f2bf(a2[2 * jj]) | ((unsigned)f2bf(a2[2 * jj + 1]) << 16);
            uint4* orow = reinterpret_cast<uint4*>(yout + (size_t)node * 64 + j0);
            orow[0] = make_uint4(pk[0], pk[1], pk[2], pk[3]);
            orow[1] = make_uint4(pk[4], pk[5], pk[6], pk[7]);
        }
    }
}

// ---------------------------------------------------------------------------
// Pool stage 1: G*PARTS blocks; block (g,part) reduces a sub-range of graph g.
// ---------------------------------------------------------------------------
#define POOL_PARTS 16
__global__ __launch_bounds__(256) void pool_partial_kernel(
    const float* __restrict__ h, const int* __restrict__ batch,
    float* __restrict__ partials, int n) {
    const int g = blockIdx.x >> 4;
    const int part = blockIdx.x & 15;
    const int tid = threadIdx.x;
    auto lb = [&](int key) {
        int lo = 0, hi = n;
        while (lo < hi) {
            int mid = (lo + hi) >> 1;
            if (batch[mid] < key) lo = mid + 1;
            else hi = mid;
        }
        return lo;
    };
    const int lo = lb(g), hi = lb(g + 1);
    const int cnt = hi - lo;
    const int s0 = lo + (int)(((long long)cnt * part) / POOL_PARTS);
    const int s1 = lo + (int)(((long long)cnt * (part + 1)) / POOL_PARTS);

    const int f = tid & 63;
    const int q = tid >> 6;
    float s = 0.f;
    for (int i = s0 + q; i < s1; i += 4) s += h[(size_t)i * 64 + f];

    __shared__ float red[256];
    red[tid] = s;
    __syncthreads();
    if (tid < 64) {
        partials[(size_t)blockIdx.x * 64 + tid] =
            red[tid] + red[tid + 64] + red[tid + 128] + red[tid + 192];
    }
}

// ---------------------------------------------------------------------------
// Pool stage 2 + head MLP. One block per graph; reads 16 partials.
// ---------------------------------------------------------------------------
__global__ __launch_bounds__(64) void pool_head_kernel(
    const float* __restrict__ partials, const int* __restrict__ batch,
    const float* __restrict__ l1w, const float* __restrict__ l1b,
    const float* __restrict__ l2w, const float* __restrict__ l2b,
    float* __restrict__ out, int n) {
    const int g = blockIdx.x;
    const int tid = threadIdx.x;
    auto lb = [&](int key) {
        int lo = 0, hi = n;
        while (lo < hi) {
            int mid = (lo + hi) >> 1;
            if (batch[mid] < key) lo = mid + 1;
            else hi = mid;
        }
        return lo;
    };
    const int cnt = lb(g + 1) - lb(g);

    __shared__ float pooled[64];
    __shared__ float r[64];
    float v = 0.f;
#pragma unroll
    for (int p = 0; p < POOL_PARTS; p++)
        v += partials[(size_t)(g * POOL_PARTS + p) * 64 + tid];
    pooled[tid] = v / (float)((cnt > 1) ? cnt : 1);
    __syncthreads();
    float a = l1b[tid];
    for (int k = 0; k < 64; k++) a = fmaf(pooled[k], l1w[k * 64 + tid], a);
    r[tid] = fmaxf(a, 0.f);
    __syncthreads();
    if (tid < 2) {
        float a2 = l2b[tid];
        for (int k = 0; k < 64; k++) a2 = fmaf(r[k], l2w[k * 2 + tid], a2);
        out[g * 2 + tid] = a2;
    }
}

// ---------------------------------------------------------------------------

extern "C" void kernel_launch(void* const* d_in, const int* in_sizes, int n_in,
                              void* d_out, int out_size, void* d_ws, size_t ws_size,
                              hipStream_t stream) {
    const float* x    = (const float*)d_in[0];
    const int* ei     = (const int*)d_in[1];
    const int* batch  = (const int*)d_in[2];
    const float* l0w1 = (const float*)d_in[3];
    const float* l0b1 = (const float*)d_in[4];
    const float* l0w2 = (const float*)d_in[5];
    const float* l0b2 = (const float*)d_in[6];
    const float* l1w1 = (const float*)d_in[7];
    const float* l1b1 = (const float*)d_in[8];
    const float* l1w2 = (const float*)d_in[9];
    const float* l1b2 = (const float*)d_in[10];
    const float* l2w1 = (const float*)d_in[11];
    const float* l2b1 = (const float*)d_in[12];
    const float* l2w2 = (const float*)d_in[13];
    const float* l2b2 = (const float*)d_in[14];
    const float* lin1w = (const float*)d_in[15];
    const float* lin1b = (const float*)d_in[16];
    const float* lin2w = (const float*)d_in[17];
    const float* lin2b = (const float*)d_in[18];
    float* out = (float*)d_out;

    const int N  = in_sizes[2];
    const int E_ = in_sizes[1] / 2;
    const int K  = (N + 511) >> 9;
    const int G  = out_size / 2;

    char* ws = (char*)d_ws;
    size_t off = 0;
    auto alloc = [&](size_t bytes) {
        void* p = ws + off;
        off += (bytes + 255) & ~(size_t)255;
        return p;
    };
    int* rowptr  = (int*)alloc((size_t)(N + 1) * 4);
    int* col     = (int*)alloc((size_t)E_ * 4);
    int* gcount  = (int*)alloc(1024 * 4);
    int* bbase   = (int*)alloc(1025 * 4);
    int* gcursor = (int*)alloc(1024 * 4);
    float* partials = (float*)alloc((size_t)G * POOL_PARTS * 64 * 4);
    unsigned short* yA = (unsigned short*)alloc((size_t)N * 64 * 2);
    unsigned short* yB = (unsigned short*)alloc((size_t)N * 64 * 2);
    float* hbuf  = (float*)alloc((size_t)N * 64 * 4);
    unsigned* bpack = (unsigned*)hbuf;  // alias: bpack dead before fused2 writes hbuf
    (void)ws_size;

    const int nch = (E_ + 2047) / 2048;

    // --- CSR build (bucketed counting sort) ---
    zero1024_kernel<<<1, 1024, 0, stream>>>(gcount);
    count_buckets_kernel<<<nch, 256, 0, stream>>>(ei, gcount, E_);
    scan_buckets_kernel<<<1, 1024, 0, stream>>>(gcount, bbase, gcursor, rowptr, K, E_, N);
    bucketize_kernel<<<nch, 256, 0, stream>>>(ei, gcursor, bpack, E_);
    build_csr_kernel<<<K, 256, 0, stream>>>(bpack, bbase, rowptr, col, N);

    const int ntiles = (N + 63) / 64;

    // layer 0 proj, then 3 fused layers
    proj128_kernel<<<ntiles, 256, 0, stream>>>(x, yA, l0w1, N);
    fused_layer_kernel<false><<<ntiles, 256, 0, stream>>>(
        yA, rowptr, col, l0b1, l0w2, l0b2, l1w1, yB, nullptr, N);
    fused_layer_kernel<false><<<ntiles, 256, 0, stream>>>(
        yB, rowptr, col, l1b1, l1w2, l1b2, l2w1, yA, nullptr, N);
    fused_layer_kernel<true><<<ntiles, 256, 0, stream>>>(
        yA, rowptr, col, l2b1, l2w2, l2b2, nullptr, nullptr, hbuf, N);

    // --- pool + head ---
    pool_partial_kernel<<<G * POOL_PARTS, 256, 0, stream>>>(hbuf, batch, partials, N);
    pool_head_kernel<<<G, 64, 0, stream>>>(partials, batch, lin1w, lin1b, lin2w, lin2b, out, N);
}